// Round 4
// baseline (675.109 us; speedup 1.0000x reference)
//
#include <hip/hip_runtime.h>

#define K_DIM 128

static __device__ __forceinline__ unsigned short f2bf(float f) {
    union { float f; unsigned u; } v; v.f = f;
    unsigned r = v.u + 0x7FFF + ((v.u >> 16) & 1);   // RNE
    return (unsigned short)(r >> 16);
}
static __device__ __forceinline__ float bf2f(unsigned short b) {
    union { unsigned u; float f; } v; v.u = ((unsigned)b) << 16;
    return v.f;
}

// ---------------------------------------------------------------------------
// Batched CSR build over all 3 layers.
// Row space: [0,100000) l0, [100000,120000) l1, [120000,125000) l2.
// ---------------------------------------------------------------------------
__global__ __launch_bounds__(256)
void count_all_kernel(const int* __restrict__ dst0, const int* __restrict__ dst1,
                      const int* __restrict__ dst2, int E0, int E1, int E2,
                      int* __restrict__ deg)
{
    int e = blockIdx.x * 256 + threadIdx.x;
    int row;
    if (e < E0)                row = dst0[e];
    else if (e < E0 + E1)      row = 100000 + dst1[e - E0];
    else if (e < E0 + E1 + E2) row = 120000 + dst2[e - E0 - E1];
    else return;
    atomicAdd(&deg[row], 1);
}

__global__ __launch_bounds__(256)
void breduce_kernel(const int* __restrict__ deg, int* __restrict__ bsum, int n)
{
    __shared__ int sm[256];
    int i = blockIdx.x * 256 + threadIdx.x;
    sm[threadIdx.x] = (i < n) ? deg[i] : 0;
    __syncthreads();
    for (int s = 128; s > 0; s >>= 1) {
        if (threadIdx.x < s) sm[threadIdx.x] += sm[threadIdx.x + s];
        __syncthreads();
    }
    if (threadIdx.x == 0) bsum[blockIdx.x] = sm[0];
}

__global__ __launch_bounds__(512)
void bscan_kernel(int* __restrict__ bsum, int nb)
{
    __shared__ int sm[512];
    int t = threadIdx.x;
    int v = (t < nb) ? bsum[t] : 0;
    sm[t] = v;
    __syncthreads();
    for (int s = 1; s < 512; s <<= 1) {
        int a = (t >= s) ? sm[t - s] : 0;
        __syncthreads();
        sm[t] += a;
        __syncthreads();
    }
    if (t < nb) bsum[t] = sm[t] - v;   // exclusive
}

__global__ __launch_bounds__(256)
void bwrite_kernel(const int* __restrict__ deg, const int* __restrict__ bsum,
                   int* __restrict__ rowstart, int* __restrict__ cursor, int n)
{
    __shared__ int sm[256];
    int t = threadIdx.x;
    int i = blockIdx.x * 256 + t;
    int v = (i < n) ? deg[i] : 0;
    sm[t] = v;
    __syncthreads();
    for (int s = 1; s < 256; s <<= 1) {
        int a = (t >= s) ? sm[t - s] : 0;
        __syncthreads();
        sm[t] += a;
        __syncthreads();
    }
    int excl = sm[t] - v + bsum[blockIdx.x];
    if (i < n) { rowstart[i] = excl; cursor[i] = excl; }
    if (i == n - 1) rowstart[n] = excl + v;
}

__global__ __launch_bounds__(256)
void fill_all_kernel(const int* __restrict__ src0, const int* __restrict__ src1,
                     const int* __restrict__ src2, const int* __restrict__ dst0,
                     const int* __restrict__ dst1, const int* __restrict__ dst2,
                     int E0, int E1, int E2,
                     int* __restrict__ cursor, int* __restrict__ csr)
{
    int e = blockIdx.x * 256 + threadIdx.x;
    int row, s;
    if (e < E0)                { row = dst0[e];                    s = src0[e]; }
    else if (e < E0 + E1)      { row = 100000 + dst1[e - E0];      s = src1[e - E0]; }
    else if (e < E0 + E1 + E2) { row = 120000 + dst2[e - E0 - E1]; s = src2[e - E0 - E1]; }
    else return;
    int pos = atomicAdd(&cursor[row], 1);
    csr[pos] = s;
}

__global__ __launch_bounds__(256)
void transpose_all_kernel(const float* __restrict__ w0s, const float* __restrict__ w0n,
                          const float* __restrict__ w1s, const float* __restrict__ w1n,
                          const float* __restrict__ w2s, const float* __restrict__ w2n,
                          float* __restrict__ wT)
{
    int idx = blockIdx.x * 256 + threadIdx.x;
    if (idx >= 81920) return;
    const float* src; int off, ncol;
    if      (idx < 16384) { src = w0s; off = 0;     ncol = 128; }
    else if (idx < 32768) { src = w0n; off = 16384; ncol = 128; }
    else if (idx < 49152) { src = w1s; off = 32768; ncol = 128; }
    else if (idx < 65536) { src = w1n; off = 49152; ncol = 128; }
    else if (idx < 73728) { src = w2s; off = 65536; ncol = 64;  }
    else                  { src = w2n; off = 73728; ncol = 64;  }
    int local = idx - off;
    int j = local >> 7;
    int k = local & 127;
    wT[off + k * ncol + j] = src[j * K_DIM + k];
}

// ---------------------------------------------------------------------------
// Gather-mean: one 32-lane group per dst row; zero LDS, max occupancy.
// mean written as bf16 (RNE).
// ---------------------------------------------------------------------------
__global__ __launch_bounds__(256)
void gather_mean_kernel(const float* __restrict__ h,
                        const int* __restrict__ csr,
                        const int* __restrict__ rs,      // rowstart + layer base
                        unsigned short* __restrict__ msgb,
                        int n)
{
    long gid = (long)blockIdx.x * 256 + threadIdx.x;
    int g = (int)(gid >> 5);
    int lane = (int)(gid & 31);
    if (g >= n) return;

    int s0 = rs[g], s1 = rs[g + 1];
    float4 acc = make_float4(0.f, 0.f, 0.f, 0.f);
    int e = s0;
    for (; e + 4 <= s1; e += 4) {
        int i0 = csr[e], i1 = csr[e + 1], i2 = csr[e + 2], i3 = csr[e + 3];
        float4 v0 = reinterpret_cast<const float4*>(h + (long)i0 * K_DIM)[lane];
        float4 v1 = reinterpret_cast<const float4*>(h + (long)i1 * K_DIM)[lane];
        float4 v2 = reinterpret_cast<const float4*>(h + (long)i2 * K_DIM)[lane];
        float4 v3 = reinterpret_cast<const float4*>(h + (long)i3 * K_DIM)[lane];
        acc.x += (v0.x + v1.x) + (v2.x + v3.x);
        acc.y += (v0.y + v1.y) + (v2.y + v3.y);
        acc.z += (v0.z + v1.z) + (v2.z + v3.z);
        acc.w += (v0.w + v1.w) + (v2.w + v3.w);
    }
    for (; e < s1; ++e) {
        int i0 = csr[e];
        float4 v0 = reinterpret_cast<const float4*>(h + (long)i0 * K_DIM)[lane];
        acc.x += v0.x; acc.y += v0.y; acc.z += v0.z; acc.w += v0.w;
    }
    float rd = 1.0f / fmaxf((float)(s1 - s0), 1.0f);
    ushort4 o;
    o.x = f2bf(acc.x * rd);
    o.y = f2bf(acc.y * rd);
    o.z = f2bf(acc.z * rd);
    o.w = f2bf(acc.w * rd);
    reinterpret_cast<ushort4*>(msgb + (long)g * K_DIM)[lane] = o;
}

// ---------------------------------------------------------------------------
// SAGE GEMM: out = act(h @ WsT + mean_bf16 @ WnT + b)
// ROWS=64, KC=16. LDS ~26 KB, pure-VALU kernel.
// ---------------------------------------------------------------------------
template<int NCOL, bool RELU>
__global__ __launch_bounds__(256, 4)
void sage_gemm_kernel(const float* __restrict__ h,
                      const unsigned short* __restrict__ msgb,
                      const float* __restrict__ WsT,   // [128][NCOL]
                      const float* __restrict__ WnT,   // [128][NCOL]
                      const float* __restrict__ bias,
                      float* __restrict__ out,
                      int n)
{
    constexpr int K    = 128;
    constexpr int KC   = 16;
    constexpr int ROWS = 64;
    constexpr int CT   = NCOL / 4;      // 32 or 16
    constexpr int RG   = 256 / CT;      // 8 or 16
    constexpr int RPT  = ROWS / RG;     // 8 or 4

    __shared__ float Ws[KC][NCOL];
    __shared__ float Wn[KC][NCOL];
    __shared__ float hs[ROWS][KC + 4];
    __shared__ float ms[ROWS][KC + 4];

    const int t    = threadIdx.x;
    const int row0 = blockIdx.x * ROWS;
    const int ct = t % CT;
    const int rg = t / CT;
    const int c0 = ct * 4;

    float acc[RPT][4];
    #pragma unroll
    for (int r = 0; r < RPT; ++r)
        #pragma unroll
        for (int cc = 0; cc < 4; ++cc) acc[r][cc] = 0.0f;

    for (int kc = 0; kc < K; kc += KC) {
        __syncthreads();

        #pragma unroll
        for (int idx = t; idx < KC * NCOL / 4; idx += 256) {
            reinterpret_cast<float4*>(&Ws[0][0])[idx] =
                reinterpret_cast<const float4*>(WsT + kc * NCOL)[idx];
            reinterpret_cast<float4*>(&Wn[0][0])[idx] =
                reinterpret_cast<const float4*>(WnT + kc * NCOL)[idx];
        }
        {   // 256 threads = 64 rows x 4 quads
            int r = t >> 2, k4 = t & 3;
            int gr = row0 + r;
            float4 hv = make_float4(0.f, 0.f, 0.f, 0.f);
            float4 mv = make_float4(0.f, 0.f, 0.f, 0.f);
            if (gr < n) {
                hv = reinterpret_cast<const float4*>(h + (long)gr * K + kc)[k4];
                ushort4 mb = reinterpret_cast<const ushort4*>(msgb + (long)gr * K + kc)[k4];
                mv.x = bf2f(mb.x); mv.y = bf2f(mb.y);
                mv.z = bf2f(mb.z); mv.w = bf2f(mb.w);
            }
            *reinterpret_cast<float4*>(&hs[r][k4 * 4]) = hv;
            *reinterpret_cast<float4*>(&ms[r][k4 * 4]) = mv;
        }
        __syncthreads();

        #pragma unroll
        for (int kk = 0; kk < KC; kk += 4) {
            float wsv[4][4], wnv[4][4];
            #pragma unroll
            for (int i = 0; i < 4; ++i) {
                float4 a = *reinterpret_cast<const float4*>(&Ws[kk + i][c0]);
                float4 b = *reinterpret_cast<const float4*>(&Wn[kk + i][c0]);
                wsv[i][0] = a.x; wsv[i][1] = a.y; wsv[i][2] = a.z; wsv[i][3] = a.w;
                wnv[i][0] = b.x; wnv[i][1] = b.y; wnv[i][2] = b.z; wnv[i][3] = b.w;
            }
            #pragma unroll
            for (int r = 0; r < RPT; ++r) {
                int row = rg * RPT + r;
                float4 hv = *reinterpret_cast<const float4*>(&hs[row][kk]);
                float4 mv = *reinterpret_cast<const float4*>(&ms[row][kk]);
                float hvv[4] = {hv.x, hv.y, hv.z, hv.w};
                float mvv[4] = {mv.x, mv.y, mv.z, mv.w};
                #pragma unroll
                for (int cc = 0; cc < 4; ++cc) {
                    float a = acc[r][cc];
                    #pragma unroll
                    for (int i = 0; i < 4; ++i) {
                        a = fmaf(hvv[i], wsv[i][cc], a);
                        a = fmaf(mvv[i], wnv[i][cc], a);
                    }
                    acc[r][cc] = a;
                }
            }
        }
    }

    #pragma unroll
    for (int r = 0; r < RPT; ++r) {
        int gr = row0 + rg * RPT + r;
        if (gr < n) {
            float4 o;
            float* op = reinterpret_cast<float*>(&o);
            #pragma unroll
            for (int cc = 0; cc < 4; ++cc) {
                float v = acc[r][cc] + bias[c0 + cc];
                if (RELU) v = fmaxf(v, 0.0f);
                op[cc] = v;
            }
            *reinterpret_cast<float4*>(out + (long)gr * NCOL + c0) = o;
        }
    }
}

// ---------------------------------------------------------------------------
// Workspace (float offsets):
//   h1:   [0, 12.8M)
//   h2:   [12.8M, 15.36M)
//   wT:   [15.36M, +81920)
//   msgb: [15.44192M, +6.4M)   (12.8M ushorts, reused per layer)
//   ints: csr(2.5M) deg(125K) rowstart(125001) cursor(125K) bsum(512)
// Total ~98.9 MB (< 102.8 MB proven in R1).
// ---------------------------------------------------------------------------
extern "C" void kernel_launch(void* const* d_in, const int* in_sizes, int n_in,
                              void* d_out, int out_size, void* d_ws, size_t ws_size,
                              hipStream_t stream)
{
    const float* feats   = (const float*)d_in[0];
    const int*   src0    = (const int*)d_in[1];
    const int*   dst0    = (const int*)d_in[2];
    const int*   src1    = (const int*)d_in[3];
    const int*   dst1    = (const int*)d_in[4];
    const int*   src2    = (const int*)d_in[5];
    const int*   dst2    = (const int*)d_in[6];
    const float* Wself0  = (const float*)d_in[10];
    const float* Wneigh0 = (const float*)d_in[11];
    const float* b0      = (const float*)d_in[12];
    const float* Wself1  = (const float*)d_in[13];
    const float* Wneigh1 = (const float*)d_in[14];
    const float* b1      = (const float*)d_in[15];
    const float* Wself2  = (const float*)d_in[16];
    const float* Wneigh2 = (const float*)d_in[17];
    const float* b2      = (const float*)d_in[18];

    const int E0 = in_sizes[1];
    const int E1 = in_sizes[3];
    const int E2 = in_sizes[5];
    const int Etot = E0 + E1 + E2;           // 2.5M
    const int NTOT = 125000;
    const int N1 = 100000, N2 = 20000, N3 = 5000;

    float* ws  = (float*)d_ws;
    float* h1  = ws;
    float* h2  = ws + 12800000;
    float* wT  = ws + 15360000;
    unsigned short* msgb = (unsigned short*)(wT + 81920);   // 12.8M ushorts
    int* csr      = (int*)(msgb + 12800000);
    int* degi     = csr + 2500000;
    int* rowstart = degi + 125000;
    int* cursor   = rowstart + 125001;
    int* bsum     = cursor + 125000;

    // ---- batched CSR build + weight transpose
    hipMemsetAsync(degi, 0, (size_t)NTOT * sizeof(int), stream);
    count_all_kernel<<<(Etot + 255) / 256, 256, 0, stream>>>(
        dst0, dst1, dst2, E0, E1, E2, degi);
    int nb = (NTOT + 255) / 256;   // 489
    breduce_kernel<<<nb, 256, 0, stream>>>(degi, bsum, NTOT);
    bscan_kernel<<<1, 512, 0, stream>>>(bsum, nb);
    bwrite_kernel<<<nb, 256, 0, stream>>>(degi, bsum, rowstart, cursor, NTOT);
    fill_all_kernel<<<(Etot + 255) / 256, 256, 0, stream>>>(
        src0, src1, src2, dst0, dst1, dst2, E0, E1, E2, cursor, csr);
    transpose_all_kernel<<<(81920 + 255) / 256, 256, 0, stream>>>(
        Wself0, Wneigh0, Wself1, Wneigh1, Wself2, Wneigh2, wT);

    // ---- layer 0: feats(500K) -> h1(100K), relu
    gather_mean_kernel<<<(int)(((long)N1 * 32 + 255) / 256), 256, 0, stream>>>(
        feats, csr, rowstart, msgb, N1);
    sage_gemm_kernel<128, true><<<(N1 + 63) / 64, 256, 0, stream>>>(
        feats, msgb, wT, wT + 16384, b0, h1, N1);

    // ---- layer 1: h1 -> h2(20K), relu
    gather_mean_kernel<<<(int)(((long)N2 * 32 + 255) / 256), 256, 0, stream>>>(
        h1, csr, rowstart + 100000, msgb, N2);
    sage_gemm_kernel<128, true><<<(N2 + 63) / 64, 256, 0, stream>>>(
        h1, msgb, wT + 32768, wT + 49152, b1, h2, N2);

    // ---- layer 2: h2 -> out(5K x 64), no relu
    gather_mean_kernel<<<(int)(((long)N3 * 32 + 255) / 256), 256, 0, stream>>>(
        h2, csr, rowstart + 120000, msgb, N3);
    sage_gemm_kernel<64, false><<<(N3 + 63) / 64, 256, 0, stream>>>(
        h2, msgb, wT + 65536, wT + 73728, b2, (float*)d_out, N3);
}

// Round 5
// 471.625 us; speedup vs baseline: 1.4315x; 1.4315x over previous
//
#include <hip/hip_runtime.h>

#define K_DIM 128
#define NTOT   125000          // 100000 + 20000 + 5000 dst rows
#define RPB    512             // rows per bucket
#define NB     245             // ceil(NTOT / RPB)

static __device__ __forceinline__ unsigned short f2bf(float f) {
    union { float f; unsigned u; } v; v.f = f;
    unsigned r = v.u + 0x7FFF + ((v.u >> 16) & 1);   // RNE
    return (unsigned short)(r >> 16);
}
static __device__ __forceinline__ float bf2f(unsigned short b) {
    union { unsigned u; float f; } v; v.u = ((unsigned)b) << 16;
    return v.f;
}

// decode edge e in the concatenated edge space -> (row, src)
static __device__ __forceinline__ void edge_decode(
    int e,
    const int* __restrict__ s0, const int* __restrict__ d0,
    const int* __restrict__ s1, const int* __restrict__ d1,
    const int* __restrict__ s2, const int* __restrict__ d2,
    int E0, int E1, int& row, int& src)
{
    if (e < E0)           { row = d0[e];                    src = s0[e]; }
    else if (e < E0 + E1) { row = 100000 + d1[e - E0];      src = s1[e - E0]; }
    else                  { row = 120000 + d2[e - E0 - E1]; src = s2[e - E0 - E1]; }
}

// ---------------------------------------------------------------------------
// Pass A: bucket histogram (LDS-aggregated)
// ---------------------------------------------------------------------------
__global__ __launch_bounds__(256)
void bucket_count_kernel(const int* __restrict__ d0, const int* __restrict__ d1,
                         const int* __restrict__ d2, int E0, int E1, int Etot,
                         int* __restrict__ bucket_cnt)
{
    __shared__ int hist[256];
    int t = threadIdx.x;
    hist[t] = 0;
    __syncthreads();
    int stride = gridDim.x * 256;
    for (int e = blockIdx.x * 256 + t; e < Etot; e += stride) {
        int row;
        if (e < E0)           row = d0[e];
        else if (e < E0 + E1) row = 100000 + d1[e - E0];
        else                  row = 120000 + d2[e - E0 - E1];
        atomicAdd(&hist[row >> 9], 1);
    }
    __syncthreads();
    if (t < NB && hist[t]) atomicAdd(&bucket_cnt[t], hist[t]);
}

// ---------------------------------------------------------------------------
// Pass B: scan bucket counts -> bucket_base[NB+1], bucket_cursor
// ---------------------------------------------------------------------------
__global__ __launch_bounds__(256)
void bucket_scan_kernel(const int* __restrict__ bucket_cnt,
                        int* __restrict__ bucket_base,
                        int* __restrict__ bucket_cursor, int Etot)
{
    __shared__ int sm[256];
    int t = threadIdx.x;
    int v = (t < NB) ? bucket_cnt[t] : 0;
    sm[t] = v;
    __syncthreads();
    for (int s = 1; s < 256; s <<= 1) {
        int a = (t >= s) ? sm[t - s] : 0;
        __syncthreads();
        sm[t] += a;
        __syncthreads();
    }
    int excl = sm[t] - v;
    if (t < NB) { bucket_base[t] = excl; bucket_cursor[t] = excl; }
    if (t == 0) bucket_base[NB] = Etot;
}

// ---------------------------------------------------------------------------
// Pass C: scatter (row,src) pairs into bucket-ordered ebuf.
// One block handles a contiguous chunk of 4096 edges; per-block reservation.
// ---------------------------------------------------------------------------
#define CHUNK 4096
__global__ __launch_bounds__(256)
void bucket_scatter_kernel(const int* __restrict__ s0, const int* __restrict__ d0,
                           const int* __restrict__ s1, const int* __restrict__ d1,
                           const int* __restrict__ s2, const int* __restrict__ d2,
                           int E0, int E1, int Etot,
                           int* __restrict__ bucket_cursor,
                           int2* __restrict__ ebuf)
{
    __shared__ int hist[256];
    __shared__ int start[256];
    int t = threadIdx.x;
    int base = blockIdx.x * CHUNK;
    hist[t] = 0;
    __syncthreads();

    #pragma unroll
    for (int i = 0; i < CHUNK / 256; ++i) {
        int e = base + i * 256 + t;
        if (e < Etot) {
            int row;
            if (e < E0)           row = d0[e];
            else if (e < E0 + E1) row = 100000 + d1[e - E0];
            else                  row = 120000 + d2[e - E0 - E1];
            atomicAdd(&hist[row >> 9], 1);
        }
    }
    __syncthreads();
    if (t < NB) {
        int c = hist[t];
        start[t] = c ? atomicAdd(&bucket_cursor[t], c) : 0;
    }
    __syncthreads();
    hist[t] = 0;
    __syncthreads();

    #pragma unroll
    for (int i = 0; i < CHUNK / 256; ++i) {
        int e = base + i * 256 + t;
        if (e < Etot) {
            int row, src;
            edge_decode(e, s0, d0, s1, d1, s2, d2, E0, E1, row, src);
            int b = row >> 9;
            int pos = start[b] + atomicAdd(&hist[b], 1);
            ebuf[pos] = make_int2(row, src);
        }
    }
}

// ---------------------------------------------------------------------------
// Pass D: per-bucket LDS counting sort -> rowstart + csr.
// One block per bucket; csr window (~40KB) stays in one XCD's L2.
// ---------------------------------------------------------------------------
__global__ __launch_bounds__(256)
void bucket_fill_kernel(const int2* __restrict__ ebuf,
                        const int* __restrict__ bucket_base,
                        int* __restrict__ rowstart,
                        int* __restrict__ csr, int Etot)
{
    __shared__ int hist[RPB];
    __shared__ int ps[256];
    __shared__ int rst[RPB];

    int t = threadIdx.x;
    int b = blockIdx.x;
    int e0 = bucket_base[b], e1 = bucket_base[b + 1];
    int row0 = b << 9;
    int nrows = min(RPB, NTOT - row0);

    hist[t] = 0; hist[t + 256] = 0;
    __syncthreads();
    for (int e = e0 + t; e < e1; e += 256)
        atomicAdd(&hist[ebuf[e].x - row0], 1);
    __syncthreads();

    // block scan over 512 bins (pairwise)
    int a0 = hist[2 * t], a1 = hist[2 * t + 1];
    int pv = a0 + a1;
    ps[t] = pv;
    __syncthreads();
    for (int s = 1; s < 256; s <<= 1) {
        int a = (t >= s) ? ps[t - s] : 0;
        __syncthreads();
        ps[t] += a;
        __syncthreads();
    }
    int pe = ps[t] - pv;          // exclusive over pairs
    rst[2 * t] = pe;
    rst[2 * t + 1] = pe + a0;
    __syncthreads();

    // write rowstart, init LDS cursors (reuse hist)
    if (2 * t < nrows)     rowstart[row0 + 2 * t]     = e0 + rst[2 * t];
    if (2 * t + 1 < nrows) rowstart[row0 + 2 * t + 1] = e0 + rst[2 * t + 1];
    if (b == NB - 1 && t == 0) rowstart[NTOT] = Etot;
    hist[2 * t] = rst[2 * t];
    hist[2 * t + 1] = rst[2 * t + 1];
    __syncthreads();

    for (int e = e0 + t; e < e1; e += 256) {
        int2 p = ebuf[e];
        int off = atomicAdd(&hist[p.x - row0], 1);
        csr[e0 + off] = p.y;
    }
}

// ---------------------------------------------------------------------------
// Weight transpose (all 6 matrices)
// ---------------------------------------------------------------------------
__global__ __launch_bounds__(256)
void transpose_all_kernel(const float* __restrict__ w0s, const float* __restrict__ w0n,
                          const float* __restrict__ w1s, const float* __restrict__ w1n,
                          const float* __restrict__ w2s, const float* __restrict__ w2n,
                          float* __restrict__ wT)
{
    int idx = blockIdx.x * 256 + threadIdx.x;
    if (idx >= 81920) return;
    const float* src; int off, ncol;
    if      (idx < 16384) { src = w0s; off = 0;     ncol = 128; }
    else if (idx < 32768) { src = w0n; off = 16384; ncol = 128; }
    else if (idx < 49152) { src = w1s; off = 32768; ncol = 128; }
    else if (idx < 65536) { src = w1n; off = 49152; ncol = 128; }
    else if (idx < 73728) { src = w2s; off = 65536; ncol = 64;  }
    else                  { src = w2n; off = 73728; ncol = 64;  }
    int local = idx - off;
    int j = local >> 7;
    int k = local & 127;
    wT[off + k * ncol + j] = src[j * K_DIM + k];
}

// ---------------------------------------------------------------------------
// Gather-mean: one 32-lane group per dst row; zero LDS, max occupancy.
// ---------------------------------------------------------------------------
__global__ __launch_bounds__(256)
void gather_mean_kernel(const float* __restrict__ h,
                        const int* __restrict__ csr,
                        const int* __restrict__ rs,
                        unsigned short* __restrict__ msgb,
                        int n)
{
    long gid = (long)blockIdx.x * 256 + threadIdx.x;
    int g = (int)(gid >> 5);
    int lane = (int)(gid & 31);
    if (g >= n) return;

    int s0 = rs[g], s1 = rs[g + 1];
    float4 acc = make_float4(0.f, 0.f, 0.f, 0.f);
    int e = s0;
    for (; e + 4 <= s1; e += 4) {
        int i0 = csr[e], i1 = csr[e + 1], i2 = csr[e + 2], i3 = csr[e + 3];
        float4 v0 = reinterpret_cast<const float4*>(h + (long)i0 * K_DIM)[lane];
        float4 v1 = reinterpret_cast<const float4*>(h + (long)i1 * K_DIM)[lane];
        float4 v2 = reinterpret_cast<const float4*>(h + (long)i2 * K_DIM)[lane];
        float4 v3 = reinterpret_cast<const float4*>(h + (long)i3 * K_DIM)[lane];
        acc.x += (v0.x + v1.x) + (v2.x + v3.x);
        acc.y += (v0.y + v1.y) + (v2.y + v3.y);
        acc.z += (v0.z + v1.z) + (v2.z + v3.z);
        acc.w += (v0.w + v1.w) + (v2.w + v3.w);
    }
    for (; e < s1; ++e) {
        int i0 = csr[e];
        float4 v0 = reinterpret_cast<const float4*>(h + (long)i0 * K_DIM)[lane];
        acc.x += v0.x; acc.y += v0.y; acc.z += v0.z; acc.w += v0.w;
    }
    float rd = 1.0f / fmaxf((float)(s1 - s0), 1.0f);
    ushort4 o;
    o.x = f2bf(acc.x * rd);
    o.y = f2bf(acc.y * rd);
    o.z = f2bf(acc.z * rd);
    o.w = f2bf(acc.w * rd);
    reinterpret_cast<ushort4*>(msgb + (long)g * K_DIM)[lane] = o;
}

// ---------------------------------------------------------------------------
// SAGE GEMM: out = act(h @ WsT + mean_bf16 @ WnT + b)
// ---------------------------------------------------------------------------
template<int NCOL, bool RELU>
__global__ __launch_bounds__(256, 4)
void sage_gemm_kernel(const float* __restrict__ h,
                      const unsigned short* __restrict__ msgb,
                      const float* __restrict__ WsT,   // [128][NCOL]
                      const float* __restrict__ WnT,   // [128][NCOL]
                      const float* __restrict__ bias,
                      float* __restrict__ out,
                      int n)
{
    constexpr int K    = 128;
    constexpr int KC   = 16;
    constexpr int ROWS = 64;
    constexpr int CT   = NCOL / 4;
    constexpr int RG   = 256 / CT;
    constexpr int RPT  = ROWS / RG;

    __shared__ float Ws[KC][NCOL];
    __shared__ float Wn[KC][NCOL];
    __shared__ float hs[ROWS][KC + 4];
    __shared__ float ms[ROWS][KC + 4];

    const int t    = threadIdx.x;
    const int row0 = blockIdx.x * ROWS;
    const int ct = t % CT;
    const int rg = t / CT;
    const int c0 = ct * 4;

    float acc[RPT][4];
    #pragma unroll
    for (int r = 0; r < RPT; ++r)
        #pragma unroll
        for (int cc = 0; cc < 4; ++cc) acc[r][cc] = 0.0f;

    for (int kc = 0; kc < K; kc += KC) {
        __syncthreads();

        #pragma unroll
        for (int idx = t; idx < KC * NCOL / 4; idx += 256) {
            reinterpret_cast<float4*>(&Ws[0][0])[idx] =
                reinterpret_cast<const float4*>(WsT + kc * NCOL)[idx];
            reinterpret_cast<float4*>(&Wn[0][0])[idx] =
                reinterpret_cast<const float4*>(WnT + kc * NCOL)[idx];
        }
        {
            int r = t >> 2, k4 = t & 3;
            int gr = row0 + r;
            float4 hv = make_float4(0.f, 0.f, 0.f, 0.f);
            float4 mv = make_float4(0.f, 0.f, 0.f, 0.f);
            if (gr < n) {
                hv = reinterpret_cast<const float4*>(h + (long)gr * K + kc)[k4];
                ushort4 mb = reinterpret_cast<const ushort4*>(msgb + (long)gr * K + kc)[k4];
                mv.x = bf2f(mb.x); mv.y = bf2f(mb.y);
                mv.z = bf2f(mb.z); mv.w = bf2f(mb.w);
            }
            *reinterpret_cast<float4*>(&hs[r][k4 * 4]) = hv;
            *reinterpret_cast<float4*>(&ms[r][k4 * 4]) = mv;
        }
        __syncthreads();

        #pragma unroll
        for (int kk = 0; kk < KC; kk += 4) {
            float wsv[4][4], wnv[4][4];
            #pragma unroll
            for (int i = 0; i < 4; ++i) {
                float4 a = *reinterpret_cast<const float4*>(&Ws[kk + i][c0]);
                float4 b = *reinterpret_cast<const float4*>(&Wn[kk + i][c0]);
                wsv[i][0] = a.x; wsv[i][1] = a.y; wsv[i][2] = a.z; wsv[i][3] = a.w;
                wnv[i][0] = b.x; wnv[i][1] = b.y; wnv[i][2] = b.z; wnv[i][3] = b.w;
            }
            #pragma unroll
            for (int r = 0; r < RPT; ++r) {
                int row = rg * RPT + r;
                float4 hv = *reinterpret_cast<const float4*>(&hs[row][kk]);
                float4 mv = *reinterpret_cast<const float4*>(&ms[row][kk]);
                float hvv[4] = {hv.x, hv.y, hv.z, hv.w};
                float mvv[4] = {mv.x, mv.y, mv.z, mv.w};
                #pragma unroll
                for (int cc = 0; cc < 4; ++cc) {
                    float a = acc[r][cc];
                    #pragma unroll
                    for (int i = 0; i < 4; ++i) {
                        a = fmaf(hvv[i], wsv[i][cc], a);
                        a = fmaf(mvv[i], wnv[i][cc], a);
                    }
                    acc[r][cc] = a;
                }
            }
        }
    }

    #pragma unroll
    for (int r = 0; r < RPT; ++r) {
        int gr = row0 + rg * RPT + r;
        if (gr < n) {
            float4 o;
            float* op = reinterpret_cast<float*>(&o);
            #pragma unroll
            for (int cc = 0; cc < 4; ++cc) {
                float v = acc[r][cc] + bias[c0 + cc];
                if (RELU) v = fmaxf(v, 0.0f);
                op[cc] = v;
            }
            *reinterpret_cast<float4*>(out + (long)gr * NCOL + c0) = o;
        }
    }
}

// ---------------------------------------------------------------------------
// Workspace (float offsets):
//   h1:    [0, 12.8M)
//   h2:    [12.8M, 15.36M)
//   wT:    [15.36M, +81920)
//   union: [15.44192M, +6.4M)   msgb (12.8M ushorts)  /  ebuf (2.5M int2) alias
//   csr:   [21.84192M, +2.5M)
//   rowstart(125001), bucket_cnt(256), bucket_base(256), bucket_cursor(256)
// Total ~98 MB.
// ---------------------------------------------------------------------------
extern "C" void kernel_launch(void* const* d_in, const int* in_sizes, int n_in,
                              void* d_out, int out_size, void* d_ws, size_t ws_size,
                              hipStream_t stream)
{
    const float* feats   = (const float*)d_in[0];
    const int*   src0    = (const int*)d_in[1];
    const int*   dst0    = (const int*)d_in[2];
    const int*   src1    = (const int*)d_in[3];
    const int*   dst1    = (const int*)d_in[4];
    const int*   src2    = (const int*)d_in[5];
    const int*   dst2    = (const int*)d_in[6];
    const float* Wself0  = (const float*)d_in[10];
    const float* Wneigh0 = (const float*)d_in[11];
    const float* b0      = (const float*)d_in[12];
    const float* Wself1  = (const float*)d_in[13];
    const float* Wneigh1 = (const float*)d_in[14];
    const float* b1      = (const float*)d_in[15];
    const float* Wself2  = (const float*)d_in[16];
    const float* Wneigh2 = (const float*)d_in[17];
    const float* b2      = (const float*)d_in[18];

    const int E0 = in_sizes[1];
    const int E1 = in_sizes[3];
    const int E2 = in_sizes[5];
    const int Etot = E0 + E1 + E2;           // 2.5M
    const int N1 = 100000, N2 = 20000, N3 = 5000;

    float* ws  = (float*)d_ws;
    float* h1  = ws;
    float* h2  = ws + 12800000;
    float* wT  = ws + 15360000;
    unsigned short* msgb = (unsigned short*)(wT + 81920);    // 12.8M ushorts
    int2* ebuf = (int2*)msgb;                                 // alias (build phase only)
    int* csr      = (int*)(msgb + 12800000);
    int* rowstart = csr + 2500000;
    int* bucket_cnt    = rowstart + 125001;
    int* bucket_base   = bucket_cnt + 256;
    int* bucket_cursor = bucket_base + 256;

    // ---- CSR build: 2-level counting sort
    hipMemsetAsync(bucket_cnt, 0, 256 * sizeof(int), stream);
    bucket_count_kernel<<<512, 256, 0, stream>>>(
        dst0, dst1, dst2, E0, E1, Etot, bucket_cnt);
    bucket_scan_kernel<<<1, 256, 0, stream>>>(
        bucket_cnt, bucket_base, bucket_cursor, Etot);
    bucket_scatter_kernel<<<(Etot + CHUNK - 1) / CHUNK, 256, 0, stream>>>(
        src0, dst0, src1, dst1, src2, dst2, E0, E1, Etot, bucket_cursor, ebuf);
    bucket_fill_kernel<<<NB, 256, 0, stream>>>(
        ebuf, bucket_base, rowstart, csr, Etot);
    transpose_all_kernel<<<(81920 + 255) / 256, 256, 0, stream>>>(
        Wself0, Wneigh0, Wself1, Wneigh1, Wself2, Wneigh2, wT);

    // ---- layer 0: feats(500K) -> h1(100K), relu
    gather_mean_kernel<<<(int)(((long)N1 * 32 + 255) / 256), 256, 0, stream>>>(
        feats, csr, rowstart, msgb, N1);
    sage_gemm_kernel<128, true><<<(N1 + 63) / 64, 256, 0, stream>>>(
        feats, msgb, wT, wT + 16384, b0, h1, N1);

    // ---- layer 1: h1 -> h2(20K), relu
    gather_mean_kernel<<<(int)(((long)N2 * 32 + 255) / 256), 256, 0, stream>>>(
        h1, csr, rowstart + 100000, msgb, N2);
    sage_gemm_kernel<128, true><<<(N2 + 63) / 64, 256, 0, stream>>>(
        h1, msgb, wT + 32768, wT + 49152, b1, h2, N2);

    // ---- layer 2: h2 -> out(5K x 64), no relu
    gather_mean_kernel<<<(int)(((long)N3 * 32 + 255) / 256), 256, 0, stream>>>(
        h2, csr, rowstart + 120000, msgb, N3);
    sage_gemm_kernel<64, false><<<(N3 + 63) / 64, 256, 0, stream>>>(
        h2, msgb, wT + 65536, wT + 73728, b2, (float*)d_out, N3);
}

// Round 6
// 377.513 us; speedup vs baseline: 1.7883x; 1.2493x over previous
//
#include <hip/hip_runtime.h>

#define K_DIM 128
#define NTOT   125000          // 100000 + 20000 + 5000 dst rows
#define RPB    512             // rows per bucket
#define NB     245             // ceil(NTOT / RPB)

typedef __attribute__((ext_vector_type(8))) short bf16x8;   // 8 bf16 = 4 VGPR
typedef __attribute__((ext_vector_type(4))) float f32x4;    // MFMA acc

static __device__ __forceinline__ unsigned short f2bf(float f) {
    union { float f; unsigned u; } v; v.f = f;
    unsigned r = v.u + 0x7FFF + ((v.u >> 16) & 1);   // RNE
    return (unsigned short)(r >> 16);
}
static __device__ __forceinline__ float bf2f(unsigned short b) {
    union { unsigned u; float f; } v; v.u = ((unsigned)b) << 16;
    return v.f;
}

// ---------------------------------------------------------------------------
// CSR build: 2-level counting sort (proven in R5, unchanged)
// ---------------------------------------------------------------------------
static __device__ __forceinline__ void edge_decode(
    int e,
    const int* __restrict__ s0, const int* __restrict__ d0,
    const int* __restrict__ s1, const int* __restrict__ d1,
    const int* __restrict__ s2, const int* __restrict__ d2,
    int E0, int E1, int& row, int& src)
{
    if (e < E0)           { row = d0[e];                    src = s0[e]; }
    else if (e < E0 + E1) { row = 100000 + d1[e - E0];      src = s1[e - E0]; }
    else                  { row = 120000 + d2[e - E0 - E1]; src = s2[e - E0 - E1]; }
}

__global__ __launch_bounds__(256)
void bucket_count_kernel(const int* __restrict__ d0, const int* __restrict__ d1,
                         const int* __restrict__ d2, int E0, int E1, int Etot,
                         int* __restrict__ bucket_cnt)
{
    __shared__ int hist[256];
    int t = threadIdx.x;
    hist[t] = 0;
    __syncthreads();
    int stride = gridDim.x * 256;
    for (int e = blockIdx.x * 256 + t; e < Etot; e += stride) {
        int row;
        if (e < E0)           row = d0[e];
        else if (e < E0 + E1) row = 100000 + d1[e - E0];
        else                  row = 120000 + d2[e - E0 - E1];
        atomicAdd(&hist[row >> 9], 1);
    }
    __syncthreads();
    if (t < NB && hist[t]) atomicAdd(&bucket_cnt[t], hist[t]);
}

__global__ __launch_bounds__(256)
void bucket_scan_kernel(const int* __restrict__ bucket_cnt,
                        int* __restrict__ bucket_base,
                        int* __restrict__ bucket_cursor, int Etot)
{
    __shared__ int sm[256];
    int t = threadIdx.x;
    int v = (t < NB) ? bucket_cnt[t] : 0;
    sm[t] = v;
    __syncthreads();
    for (int s = 1; s < 256; s <<= 1) {
        int a = (t >= s) ? sm[t - s] : 0;
        __syncthreads();
        sm[t] += a;
        __syncthreads();
    }
    int excl = sm[t] - v;
    if (t < NB) { bucket_base[t] = excl; bucket_cursor[t] = excl; }
    if (t == 0) bucket_base[NB] = Etot;
}

#define CHUNK 4096
__global__ __launch_bounds__(256)
void bucket_scatter_kernel(const int* __restrict__ s0, const int* __restrict__ d0,
                           const int* __restrict__ s1, const int* __restrict__ d1,
                           const int* __restrict__ s2, const int* __restrict__ d2,
                           int E0, int E1, int Etot,
                           int* __restrict__ bucket_cursor,
                           int2* __restrict__ ebuf)
{
    __shared__ int hist[256];
    __shared__ int start[256];
    int t = threadIdx.x;
    int base = blockIdx.x * CHUNK;
    hist[t] = 0;
    __syncthreads();

    #pragma unroll
    for (int i = 0; i < CHUNK / 256; ++i) {
        int e = base + i * 256 + t;
        if (e < Etot) {
            int row;
            if (e < E0)           row = d0[e];
            else if (e < E0 + E1) row = 100000 + d1[e - E0];
            else                  row = 120000 + d2[e - E0 - E1];
            atomicAdd(&hist[row >> 9], 1);
        }
    }
    __syncthreads();
    if (t < NB) {
        int c = hist[t];
        start[t] = c ? atomicAdd(&bucket_cursor[t], c) : 0;
    }
    __syncthreads();
    hist[t] = 0;
    __syncthreads();

    #pragma unroll
    for (int i = 0; i < CHUNK / 256; ++i) {
        int e = base + i * 256 + t;
        if (e < Etot) {
            int row, src;
            edge_decode(e, s0, d0, s1, d1, s2, d2, E0, E1, row, src);
            int b = row >> 9;
            int pos = start[b] + atomicAdd(&hist[b], 1);
            ebuf[pos] = make_int2(row, src);
        }
    }
}

__global__ __launch_bounds__(256)
void bucket_fill_kernel(const int2* __restrict__ ebuf,
                        const int* __restrict__ bucket_base,
                        int* __restrict__ rowstart,
                        int* __restrict__ csr, int Etot)
{
    __shared__ int hist[RPB];
    __shared__ int ps[256];
    __shared__ int rst[RPB];

    int t = threadIdx.x;
    int b = blockIdx.x;
    int e0 = bucket_base[b], e1 = bucket_base[b + 1];
    int row0 = b << 9;
    int nrows = min(RPB, NTOT - row0);

    hist[t] = 0; hist[t + 256] = 0;
    __syncthreads();
    for (int e = e0 + t; e < e1; e += 256)
        atomicAdd(&hist[ebuf[e].x - row0], 1);
    __syncthreads();

    int a0 = hist[2 * t], a1 = hist[2 * t + 1];
    int pv = a0 + a1;
    ps[t] = pv;
    __syncthreads();
    for (int s = 1; s < 256; s <<= 1) {
        int a = (t >= s) ? ps[t - s] : 0;
        __syncthreads();
        ps[t] += a;
        __syncthreads();
    }
    int pe = ps[t] - pv;
    rst[2 * t] = pe;
    rst[2 * t + 1] = pe + a0;
    __syncthreads();

    if (2 * t < nrows)     rowstart[row0 + 2 * t]     = e0 + rst[2 * t];
    if (2 * t + 1 < nrows) rowstart[row0 + 2 * t + 1] = e0 + rst[2 * t + 1];
    if (b == NB - 1 && t == 0) rowstart[NTOT] = Etot;
    hist[2 * t] = rst[2 * t];
    hist[2 * t + 1] = rst[2 * t + 1];
    __syncthreads();

    for (int e = e0 + t; e < e1; e += 256) {
        int2 p = ebuf[e];
        int off = atomicAdd(&hist[p.x - row0], 1);
        csr[e0 + off] = p.y;
    }
}

// ---------------------------------------------------------------------------
// Weight prep: split all 6 W into bf16 planes. Layout in wbf (ushort):
//  L0: ws@0      wnh@16384  wnl@32768
//  L1: ws@49152  wnh@65536  wnl@81920
//  L2: ws@98304  wnh@106496 wnl@114688          total 122880 ushorts
// ---------------------------------------------------------------------------
__global__ __launch_bounds__(256)
void conv_w_kernel(const float* __restrict__ w0s, const float* __restrict__ w0n,
                   const float* __restrict__ w1s, const float* __restrict__ w1n,
                   const float* __restrict__ w2s, const float* __restrict__ w2n,
                   unsigned short* __restrict__ wbf)
{
    int idx = blockIdx.x * 256 + threadIdx.x;
    if (idx >= 81920) return;
    if (idx < 16384) {
        wbf[idx] = f2bf(w0s[idx]);
    } else if (idx < 32768) {
        int i = idx - 16384; float v = w0n[i];
        unsigned short hi = f2bf(v);
        wbf[16384 + i] = hi;
        wbf[32768 + i] = f2bf(v - bf2f(hi));
    } else if (idx < 49152) {
        int i = idx - 32768;
        wbf[49152 + i] = f2bf(w1s[i]);
    } else if (idx < 65536) {
        int i = idx - 49152; float v = w1n[i];
        unsigned short hi = f2bf(v);
        wbf[65536 + i] = hi;
        wbf[81920 + i] = f2bf(v - bf2f(hi));
    } else if (idx < 73728) {
        int i = idx - 65536;
        wbf[98304 + i] = f2bf(w2s[i]);
    } else {
        int i = idx - 73728; float v = w2n[i];
        unsigned short hi = f2bf(v);
        wbf[106496 + i] = hi;
        wbf[114688 + i] = f2bf(v - bf2f(hi));
    }
}

// ---------------------------------------------------------------------------
// feats f32 -> bf16 plane (streaming)
// ---------------------------------------------------------------------------
__global__ __launch_bounds__(256)
void conv_feat_kernel(const float* __restrict__ src,
                      unsigned short* __restrict__ dst, int nchunk)
{
    int stride = gridDim.x * 256;
    for (int i = blockIdx.x * 256 + threadIdx.x; i < nchunk; i += stride) {
        float4 a = reinterpret_cast<const float4*>(src)[2 * (long)i];
        float4 b = reinterpret_cast<const float4*>(src)[2 * (long)i + 1];
        uint4 o;
        o.x = (unsigned)f2bf(a.x) | ((unsigned)f2bf(a.y) << 16);
        o.y = (unsigned)f2bf(a.z) | ((unsigned)f2bf(a.w) << 16);
        o.z = (unsigned)f2bf(b.x) | ((unsigned)f2bf(b.y) << 16);
        o.w = (unsigned)f2bf(b.z) | ((unsigned)f2bf(b.w) << 16);
        reinterpret_cast<uint4*>(dst)[i] = o;
    }
}

// ---------------------------------------------------------------------------
// Gather-mean, f32 source (fallback path; proven in R5)
// ---------------------------------------------------------------------------
__global__ __launch_bounds__(256)
void gather_mean_f32_kernel(const float* __restrict__ h,
                            const int* __restrict__ csr,
                            const int* __restrict__ rs,
                            unsigned short* __restrict__ msgb, int n)
{
    long gid = (long)blockIdx.x * 256 + threadIdx.x;
    int g = (int)(gid >> 5);
    int lane = (int)(gid & 31);
    if (g >= n) return;

    int s0 = rs[g], s1 = rs[g + 1];
    float4 acc = make_float4(0.f, 0.f, 0.f, 0.f);
    int e = s0;
    for (; e + 4 <= s1; e += 4) {
        int i0 = csr[e], i1 = csr[e + 1], i2 = csr[e + 2], i3 = csr[e + 3];
        float4 v0 = reinterpret_cast<const float4*>(h + (long)i0 * K_DIM)[lane];
        float4 v1 = reinterpret_cast<const float4*>(h + (long)i1 * K_DIM)[lane];
        float4 v2 = reinterpret_cast<const float4*>(h + (long)i2 * K_DIM)[lane];
        float4 v3 = reinterpret_cast<const float4*>(h + (long)i3 * K_DIM)[lane];
        acc.x += (v0.x + v1.x) + (v2.x + v3.x);
        acc.y += (v0.y + v1.y) + (v2.y + v3.y);
        acc.z += (v0.z + v1.z) + (v2.z + v3.z);
        acc.w += (v0.w + v1.w) + (v2.w + v3.w);
    }
    for (; e < s1; ++e) {
        int i0 = csr[e];
        float4 v0 = reinterpret_cast<const float4*>(h + (long)i0 * K_DIM)[lane];
        acc.x += v0.x; acc.y += v0.y; acc.z += v0.z; acc.w += v0.w;
    }
    float rd = 1.0f / fmaxf((float)(s1 - s0), 1.0f);
    ushort4 o;
    o.x = f2bf(acc.x * rd); o.y = f2bf(acc.y * rd);
    o.z = f2bf(acc.z * rd); o.w = f2bf(acc.w * rd);
    reinterpret_cast<ushort4*>(msgb + (long)g * K_DIM)[lane] = o;
}

// ---------------------------------------------------------------------------
// Gather-mean, bf16 source (half traffic; table L3-resident). 8-deep MLP.
// ---------------------------------------------------------------------------
__global__ __launch_bounds__(256)
void gather_mean_bf_kernel(const unsigned short* __restrict__ hb,
                           const int* __restrict__ csr,
                           const int* __restrict__ rs,
                           unsigned short* __restrict__ msgb, int n)
{
    long gid = (long)blockIdx.x * 256 + threadIdx.x;
    int g = (int)(gid >> 5);
    int lane = (int)(gid & 31);
    if (g >= n) return;

    int s0 = rs[g], s1 = rs[g + 1];
    float a0 = 0.f, a1 = 0.f, a2 = 0.f, a3 = 0.f;
    int e = s0;
    for (; e + 8 <= s1; e += 8) {
        int idx[8];
        #pragma unroll
        for (int i = 0; i < 8; ++i) idx[i] = csr[e + i];
        #pragma unroll
        for (int i = 0; i < 8; ++i) {
            ushort4 v = reinterpret_cast<const ushort4*>(hb + (long)idx[i] * K_DIM)[lane];
            a0 += bf2f(v.x); a1 += bf2f(v.y); a2 += bf2f(v.z); a3 += bf2f(v.w);
        }
    }
    for (; e < s1; ++e) {
        ushort4 v = reinterpret_cast<const ushort4*>(hb + (long)csr[e] * K_DIM)[lane];
        a0 += bf2f(v.x); a1 += bf2f(v.y); a2 += bf2f(v.z); a3 += bf2f(v.w);
    }
    float rd = 1.0f / fmaxf((float)(s1 - s0), 1.0f);
    ushort4 o;
    o.x = f2bf(a0 * rd); o.y = f2bf(a1 * rd);
    o.z = f2bf(a2 * rd); o.w = f2bf(a3 * rd);
    reinterpret_cast<ushort4*>(msgb + (long)g * K_DIM)[lane] = o;
}

// ---------------------------------------------------------------------------
// MFMA SAGE GEMM: out = act( h@Ws^T (split h: hi,lo) + m@Wn^T (split Wn) + b )
// 16x16x32 bf16 MFMA. Block 256 thr = 4 waves; M-tile 128; wave = 32 rows x NCOL.
// Fragment maps (gfx950): A: lane->(row=l&15, k=8*(l>>4)+j); B: (col=l&15,
// k=8*(l>>4)+j); D: (col=l&15, row=4*(l>>4)+reg)  [C/D HW-verified, m89].
// LDS is frag-linear: every frag read = base + lane*16B (conflict-free).
// ---------------------------------------------------------------------------
template<int NCOL, bool RELU, bool WRITE_BF>
__global__ __launch_bounds__(256, 3)
void sage_gemm_mfma(const float* __restrict__ h,            // [>=n][128] f32
                    const unsigned short* __restrict__ msgb,// [n][128] bf16
                    const unsigned short* __restrict__ wsb, // [NCOL][128] bf16
                    const unsigned short* __restrict__ wnh, // [NCOL][128] bf16 hi
                    const unsigned short* __restrict__ wnl, // [NCOL][128] bf16 lo
                    const float* __restrict__ bias,
                    float* __restrict__ out,                // [n][NCOL] f32
                    unsigned short* __restrict__ outb,      // [n][NCOL] bf16
                    int n)
{
    constexpr int NCB = NCOL / 16;        // 8 or 4
    __shared__ bf16x8 Ah[8][64];
    __shared__ bf16x8 Al[8][64];
    __shared__ bf16x8 Ms[8][64];
    __shared__ bf16x8 Bs[NCB][64];
    __shared__ bf16x8 Bh[NCB][64];
    __shared__ bf16x8 Bl[NCB][64];

    const int t    = threadIdx.x;
    const int lane = t & 63;
    const int w    = t >> 6;
    const int row0 = blockIdx.x * 128;

    f32x4 acc[2][NCB];
    #pragma unroll
    for (int rf = 0; rf < 2; ++rf)
        #pragma unroll
        for (int cb = 0; cb < NCB; ++cb)
            acc[rf][cb] = (f32x4){0.f, 0.f, 0.f, 0.f};

    const int arow   = t & 127;
    const int ah2    = t >> 7;
    const int grow_a = min(row0 + arow, n - 1);
    const int arb    = arow >> 4;

    for (int kc = 0; kc < 128; kc += 32) {
        __syncthreads();
        // ---- stage A (hi/lo split in-register) + M (copy) : 2 chunks/thread
        #pragma unroll
        for (int i = 0; i < 2; ++i) {
            int hh = ah2 * 2 + i;                  // 0..3
            const float* src = h + (long)grow_a * 128 + kc + hh * 8;
            float4 x = *reinterpret_cast<const float4*>(src);
            float4 y = *reinterpret_cast<const float4*>(src + 4);
            float xs[8] = {x.x, x.y, x.z, x.w, y.x, y.y, y.z, y.w};
            bf16x8 hi8, lo8;
            #pragma unroll
            for (int j = 0; j < 8; ++j) {
                unsigned short hu = f2bf(xs[j]);
                hi8[j] = (short)hu;
                lo8[j] = (short)f2bf(xs[j] - bf2f(hu));
            }
            int li = hh * 16 + (arow & 15);
            Ah[arb][li] = hi8;
            Al[arb][li] = lo8;
            Ms[arb][li] = *reinterpret_cast<const bf16x8*>(
                              msgb + (long)grow_a * 128 + kc + hh * 8);
        }
        // ---- stage B (pure 16B copies from pre-split planes)
        if (NCOL == 128) {
            int col = t & 127, h2 = t >> 7;
            #pragma unroll
            for (int i = 0; i < 2; ++i) {
                int hh = h2 * 2 + i;
                int li = hh * 16 + (col & 15);
                int cb = col >> 4;
                long o = (long)col * 128 + kc + hh * 8;
                Bs[cb][li] = *reinterpret_cast<const bf16x8*>(wsb + o);
                Bh[cb][li] = *reinterpret_cast<const bf16x8*>(wnh + o);
                Bl[cb][li] = *reinterpret_cast<const bf16x8*>(wnl + o);
            }
        } else {
            int col = t & 63, hh = t >> 6;
            int li = hh * 16 + (col & 15);
            int cb = col >> 4;
            long o = (long)col * 128 + kc + hh * 8;
            Bs[cb][li] = *reinterpret_cast<const bf16x8*>(wsb + o);
            Bh[cb][li] = *reinterpret_cast<const bf16x8*>(wnh + o);
            Bl[cb][li] = *reinterpret_cast<const bf16x8*>(wnl + o);
        }
        __syncthreads();

        // ---- MFMA: wave w owns rowblocks 2w, 2w+1
        bf16x8 a0h = Ah[2 * w][lane],     a0l = Al[2 * w][lane],     m0 = Ms[2 * w][lane];
        bf16x8 a1h = Ah[2 * w + 1][lane], a1l = Al[2 * w + 1][lane], m1 = Ms[2 * w + 1][lane];
        #pragma unroll
        for (int cb = 0; cb < NCB; ++cb) {
            bf16x8 bs = Bs[cb][lane];
            bf16x8 bh = Bh[cb][lane];
            bf16x8 bl = Bl[cb][lane];
            acc[0][cb] = __builtin_amdgcn_mfma_f32_16x16x32_bf16(a0h, bs, acc[0][cb], 0, 0, 0);
            acc[0][cb] = __builtin_amdgcn_mfma_f32_16x16x32_bf16(a0l, bs, acc[0][cb], 0, 0, 0);
            acc[0][cb] = __builtin_amdgcn_mfma_f32_16x16x32_bf16(m0,  bh, acc[0][cb], 0, 0, 0);
            acc[0][cb] = __builtin_amdgcn_mfma_f32_16x16x32_bf16(m0,  bl, acc[0][cb], 0, 0, 0);
            acc[1][cb] = __builtin_amdgcn_mfma_f32_16x16x32_bf16(a1h, bs, acc[1][cb], 0, 0, 0);
            acc[1][cb] = __builtin_amdgcn_mfma_f32_16x16x32_bf16(a1l, bs, acc[1][cb], 0, 0, 0);
            acc[1][cb] = __builtin_amdgcn_mfma_f32_16x16x32_bf16(m1,  bh, acc[1][cb], 0, 0, 0);
            acc[1][cb] = __builtin_amdgcn_mfma_f32_16x16x32_bf16(m1,  bl, acc[1][cb], 0, 0, 0);
        }
    }

    // ---- epilogue: D map col=lane&15, row=4*(lane>>4)+reg
    #pragma unroll
    for (int rf = 0; rf < 2; ++rf) {
        #pragma unroll
        for (int cb = 0; cb < NCB; ++cb) {
            int col = cb * 16 + (lane & 15);
            float bv = bias[col];
            #pragma unroll
            for (int r = 0; r < 4; ++r) {
                int grow = row0 + w * 32 + rf * 16 + (lane >> 4) * 4 + r;
                if (grow < n) {
                    float v = acc[rf][cb][r] + bv;
                    if (RELU) v = fmaxf(v, 0.f);
                    out[(long)grow * NCOL + col] = v;
                    if (WRITE_BF) outb[(long)grow * NCOL + col] = f2bf(v);
                }
            }
        }
    }
}

// ---------------------------------------------------------------------------
// Host. Two workspace layouts selected by ws_size (deterministic):
//  bf16 path (needs ~164.4 MB): feats_bf@0 (128MB, later aliased by
//    h1 f32@0 / h1_bf@51.2M / h2@76.8M / h2_bf@87.04M — lifetimes disjoint),
//    msgb@128M (25.6MB, aliases ebuf), csr@153.6M, rowstart@163.6M,
//    buckets@164.1M, wbf@164.103M.
//  f32 path (~97.8 MB): h1@0, h2@51.2M, msgb@61.44M (alias ebuf),
//    csr@87.04M, rowstart@97.04M, buckets, wbf.
// ---------------------------------------------------------------------------
extern "C" void kernel_launch(void* const* d_in, const int* in_sizes, int n_in,
                              void* d_out, int out_size, void* d_ws, size_t ws_size,
                              hipStream_t stream)
{
    const float* feats   = (const float*)d_in[0];
    const int*   src0    = (const int*)d_in[1];
    const int*   dst0    = (const int*)d_in[2];
    const int*   src1    = (const int*)d_in[3];
    const int*   dst1    = (const int*)d_in[4];
    const int*   src2    = (const int*)d_in[5];
    const int*   dst2    = (const int*)d_in[6];
    const float* Wself0  = (const float*)d_in[10];
    const float* Wneigh0 = (const float*)d_in[11];
    const float* b0      = (const float*)d_in[12];
    const float* Wself1  = (const float*)d_in[13];
    const float* Wneigh1 = (const float*)d_in[14];
    const float* b1      = (const float*)d_in[15];
    const float* Wself2  = (const float*)d_in[16];
    const float* Wneigh2 = (const float*)d_in[17];
    const float* b2      = (const float*)d_in[18];

    const int E0 = in_sizes[1];
    const int E1 = in_sizes[3];
    const int E2 = in_sizes[5];
    const int Etot = E0 + E1 + E2;
    const int N1 = 100000, N2 = 20000, N3 = 5000;

    char* base = (char*)d_ws;
    const bool bfp = ws_size >= 164500000ull;

    unsigned short* feats_bf; float* h1; unsigned short* h1b;
    float* h2; unsigned short* h2b;
    unsigned short* msgb; int2* ebuf; int* csr; int* rowstart;
    int* bcnt; int* bbase; int* bcur; unsigned short* wbf;

    if (bfp) {
        feats_bf = (unsigned short*)base;                  // 128,000,000 B
        h1   = (float*)base;                               // alias, post-gather-L0
        h1b  = (unsigned short*)(base + 51200000);
        h2   = (float*)(base + 76800000);
        h2b  = (unsigned short*)(base + 87040000);
        msgb = (unsigned short*)(base + 128000000);        // 25,600,000 B
        csr      = (int*)(base + 153600000);               // 10,000,000 B
        rowstart = (int*)(base + 163600000);               //    500,224 B
        bcnt     = (int*)(base + 164100224);
        bbase    = bcnt + 256;
        bcur     = bbase + 256;
        wbf      = (unsigned short*)(base + 164103296);    //    245,760 B
    } else {
        feats_bf = nullptr;
        h1   = (float*)base;                               // 51,200,000 B
        h1b  = nullptr;
        h2   = (float*)(base + 51200000);                  // 10,240,000 B
        h2b  = nullptr;
        msgb = (unsigned short*)(base + 61440000);         // 25,600,000 B
        csr      = (int*)(base + 87040000);
        rowstart = (int*)(base + 97040000);
        bcnt     = (int*)(base + 97540224);
        bbase    = bcnt + 256;
        bcur     = bbase + 256;
        wbf      = (unsigned short*)(base + 97543296);
    }
    ebuf = (int2*)msgb;   // build-phase alias (20 MB <= 25.6 MB)

    // ---- CSR build + weight prep
    hipMemsetAsync(bcnt, 0, 1024, stream);
    bucket_count_kernel<<<512, 256, 0, stream>>>(dst0, dst1, dst2, E0, E1, Etot, bcnt);
    bucket_scan_kernel<<<1, 256, 0, stream>>>(bcnt, bbase, bcur, Etot);
    bucket_scatter_kernel<<<(Etot + CHUNK - 1) / CHUNK, 256, 0, stream>>>(
        src0, dst0, src1, dst1, src2, dst2, E0, E1, Etot, bcur, ebuf);
    bucket_fill_kernel<<<NB, 256, 0, stream>>>(ebuf, bbase, rowstart, csr, Etot);
    conv_w_kernel<<<320, 256, 0, stream>>>(Wself0, Wneigh0, Wself1, Wneigh1,
                                           Wself2, Wneigh2, wbf);

    if (bfp) {
        conv_feat_kernel<<<4096, 256, 0, stream>>>(feats, feats_bf, 8000000);

        // layer 0
        gather_mean_bf_kernel<<<(N1 * 32 + 255) / 256, 256, 0, stream>>>(
            feats_bf, csr, rowstart, msgb, N1);
        sage_gemm_mfma<128, true, true><<<(N1 + 127) / 128, 256, 0, stream>>>(
            feats, msgb, wbf, wbf + 16384, wbf + 32768, b0, h1, h1b, N1);
        // layer 1
        gather_mean_bf_kernel<<<(N2 * 32 + 255) / 256, 256, 0, stream>>>(
            h1b, csr, rowstart + 100000, msgb, N2);
        sage_gemm_mfma<128, true, true><<<(N2 + 127) / 128, 256, 0, stream>>>(
            h1, msgb, wbf + 49152, wbf + 65536, wbf + 81920, b1, h2, h2b, N2);
        // layer 2
        gather_mean_bf_kernel<<<(N3 * 32 + 255) / 256, 256, 0, stream>>>(
            h2b, csr, rowstart + 120000, msgb, N3);
        sage_gemm_mfma<64, false, false><<<(N3 + 127) / 128, 256, 0, stream>>>(
            h2, msgb, wbf + 98304, wbf + 106496, wbf + 114688, b2,
            (float*)d_out, nullptr, N3);
    } else {
        // layer 0
        gather_mean_f32_kernel<<<(N1 * 32 + 255) / 256, 256, 0, stream>>>(
            feats, csr, rowstart, msgb, N1);
        sage_gemm_mfma<128, true, false><<<(N1 + 127) / 128, 256, 0, stream>>>(
            feats, msgb, wbf, wbf + 16384, wbf + 32768, b0, h1, nullptr, N1);
        // layer 1
        gather_mean_f32_kernel<<<(N2 * 32 + 255) / 256, 256, 0, stream>>>(
            h1, csr, rowstart + 100000, msgb, N2);
        sage_gemm_mfma<128, true, false><<<(N2 + 127) / 128, 256, 0, stream>>>(
            h1, msgb, wbf + 49152, wbf + 65536, wbf + 81920, b1, h2, nullptr, N2);
        // layer 2
        gather_mean_f32_kernel<<<(N3 * 32 + 255) / 256, 256, 0, stream>>>(
            h2, csr, rowstart + 120000, msgb, N3);
        sage_gemm_mfma<64, false, false><<<(N3 + 127) / 128, 256, 0, stream>>>(
            h2, msgb, wbf + 98304, wbf + 106496, wbf + 114688, b2,
            (float*)d_out, nullptr, N3);
    }
}

// Round 7
// 356.825 us; speedup vs baseline: 1.8920x; 1.0580x over previous
//
#include <hip/hip_runtime.h>

#define K_DIM 128
#define NTOT   125000          // 100000 + 20000 + 5000 dst rows
#define RPB    512             // rows per bucket
#define NB     245             // ceil(NTOT / RPB)

typedef __attribute__((ext_vector_type(8))) short bf16x8;           // 8 bf16 = 4 VGPR
typedef __attribute__((ext_vector_type(8))) unsigned short u16x8;   // 16 B
typedef __attribute__((ext_vector_type(4))) float f32x4;            // MFMA acc

static __device__ __forceinline__ unsigned short f2bf(float f) {
    union { float f; unsigned u; } v; v.f = f;
    unsigned r = v.u + 0x7FFF + ((v.u >> 16) & 1);   // RNE
    return (unsigned short)(r >> 16);
}
static __device__ __forceinline__ float bf2f(unsigned short b) {
    union { unsigned u; float f; } v; v.u = ((unsigned)b) << 16;
    return v.f;
}

// ---------------------------------------------------------------------------
// Fused prep: blocks [0,CFB) convert feats->bf16; [CFB,CFB+320) split W planes;
// [CFB+320, CFB+320+512) bucket-histogram the dst arrays. All independent.
// ---------------------------------------------------------------------------
__global__ __launch_bounds__(256)
void prep_kernel(const float* __restrict__ feats, unsigned short* __restrict__ feats_bf,
                 int nchunk, int CFB,
                 const float* __restrict__ w0s, const float* __restrict__ w0n,
                 const float* __restrict__ w1s, const float* __restrict__ w1n,
                 const float* __restrict__ w2s, const float* __restrict__ w2n,
                 unsigned short* __restrict__ wbf,
                 const int* __restrict__ d0, const int* __restrict__ d1,
                 const int* __restrict__ d2, int E0, int E1, int Etot,
                 int* __restrict__ bucket_cnt)
{
    __shared__ int hist[256];
    int b = blockIdx.x;
    int t = threadIdx.x;

    if (b < CFB) {                       // ---- conv_feat (grid-strided)
        int stride = CFB * 256;
        for (int i = b * 256 + t; i < nchunk; i += stride) {
            float4 a = reinterpret_cast<const float4*>(feats)[2 * (long)i];
            float4 c = reinterpret_cast<const float4*>(feats)[2 * (long)i + 1];
            uint4 o;
            o.x = (unsigned)f2bf(a.x) | ((unsigned)f2bf(a.y) << 16);
            o.y = (unsigned)f2bf(a.z) | ((unsigned)f2bf(a.w) << 16);
            o.z = (unsigned)f2bf(c.x) | ((unsigned)f2bf(c.y) << 16);
            o.w = (unsigned)f2bf(c.z) | ((unsigned)f2bf(c.w) << 16);
            reinterpret_cast<uint4*>(feats_bf)[i] = o;
        }
    } else if (b < CFB + 320) {          // ---- conv_w (split planes)
        int idx = (b - CFB) * 256 + t;
        if (idx >= 81920) return;
        if (idx < 16384) {
            wbf[idx] = f2bf(w0s[idx]);
        } else if (idx < 32768) {
            int i = idx - 16384; float v = w0n[i];
            unsigned short hi = f2bf(v);
            wbf[16384 + i] = hi;
            wbf[32768 + i] = f2bf(v - bf2f(hi));
        } else if (idx < 49152) {
            int i = idx - 32768;
            wbf[49152 + i] = f2bf(w1s[i]);
        } else if (idx < 65536) {
            int i = idx - 49152; float v = w1n[i];
            unsigned short hi = f2bf(v);
            wbf[65536 + i] = hi;
            wbf[81920 + i] = f2bf(v - bf2f(hi));
        } else if (idx < 73728) {
            int i = idx - 65536;
            wbf[98304 + i] = f2bf(w2s[i]);
        } else {
            int i = idx - 73728; float v = w2n[i];
            unsigned short hi = f2bf(v);
            wbf[106496 + i] = hi;
            wbf[114688 + i] = f2bf(v - bf2f(hi));
        }
    } else {                             // ---- bucket_count (512 blocks)
        hist[t] = 0;
        __syncthreads();
        int cb = b - CFB - 320;
        int stride = 512 * 256;
        for (int e = cb * 256 + t; e < Etot; e += stride) {
            int row;
            if (e < E0)           row = d0[e];
            else if (e < E0 + E1) row = 100000 + d1[e - E0];
            else                  row = 120000 + d2[e - E0 - E1];
            atomicAdd(&hist[row >> 9], 1);
        }
        __syncthreads();
        if (t < NB && hist[t]) atomicAdd(&bucket_cnt[t], hist[t]);
    }
}

// ---------------------------------------------------------------------------
// CSR build passes B/C/D (proven R5, unchanged)
// ---------------------------------------------------------------------------
static __device__ __forceinline__ void edge_decode(
    int e,
    const int* __restrict__ s0, const int* __restrict__ d0,
    const int* __restrict__ s1, const int* __restrict__ d1,
    const int* __restrict__ s2, const int* __restrict__ d2,
    int E0, int E1, int& row, int& src)
{
    if (e < E0)           { row = d0[e];                    src = s0[e]; }
    else if (e < E0 + E1) { row = 100000 + d1[e - E0];      src = s1[e - E0]; }
    else                  { row = 120000 + d2[e - E0 - E1]; src = s2[e - E0 - E1]; }
}

__global__ __launch_bounds__(256)
void bucket_scan_kernel(const int* __restrict__ bucket_cnt,
                        int* __restrict__ bucket_base,
                        int* __restrict__ bucket_cursor, int Etot)
{
    __shared__ int sm[256];
    int t = threadIdx.x;
    int v = (t < NB) ? bucket_cnt[t] : 0;
    sm[t] = v;
    __syncthreads();
    for (int s = 1; s < 256; s <<= 1) {
        int a = (t >= s) ? sm[t - s] : 0;
        __syncthreads();
        sm[t] += a;
        __syncthreads();
    }
    int excl = sm[t] - v;
    if (t < NB) { bucket_base[t] = excl; bucket_cursor[t] = excl; }
    if (t == 0) bucket_base[NB] = Etot;
}

#define CHUNK 4096
__global__ __launch_bounds__(256)
void bucket_scatter_kernel(const int* __restrict__ s0, const int* __restrict__ d0,
                           const int* __restrict__ s1, const int* __restrict__ d1,
                           const int* __restrict__ s2, const int* __restrict__ d2,
                           int E0, int E1, int Etot,
                           int* __restrict__ bucket_cursor,
                           int2* __restrict__ ebuf)
{
    __shared__ int hist[256];
    __shared__ int start[256];
    int t = threadIdx.x;
    int base = blockIdx.x * CHUNK;
    hist[t] = 0;
    __syncthreads();

    #pragma unroll
    for (int i = 0; i < CHUNK / 256; ++i) {
        int e = base + i * 256 + t;
        if (e < Etot) {
            int row;
            if (e < E0)           row = d0[e];
            else if (e < E0 + E1) row = 100000 + d1[e - E0];
            else                  row = 120000 + d2[e - E0 - E1];
            atomicAdd(&hist[row >> 9], 1);
        }
    }
    __syncthreads();
    if (t < NB) {
        int c = hist[t];
        start[t] = c ? atomicAdd(&bucket_cursor[t], c) : 0;
    }
    __syncthreads();
    hist[t] = 0;
    __syncthreads();

    #pragma unroll
    for (int i = 0; i < CHUNK / 256; ++i) {
        int e = base + i * 256 + t;
        if (e < Etot) {
            int row, src;
            edge_decode(e, s0, d0, s1, d1, s2, d2, E0, E1, row, src);
            int b = row >> 9;
            int pos = start[b] + atomicAdd(&hist[b], 1);
            ebuf[pos] = make_int2(row, src);
        }
    }
}

__global__ __launch_bounds__(256)
void bucket_fill_kernel(const int2* __restrict__ ebuf,
                        const int* __restrict__ bucket_base,
                        int* __restrict__ rowstart,
                        int* __restrict__ csr, int Etot)
{
    __shared__ int hist[RPB];
    __shared__ int ps[256];
    __shared__ int rst[RPB];

    int t = threadIdx.x;
    int b = blockIdx.x;
    int e0 = bucket_base[b], e1 = bucket_base[b + 1];
    int row0 = b << 9;
    int nrows = min(RPB, NTOT - row0);

    hist[t] = 0; hist[t + 256] = 0;
    __syncthreads();
    for (int e = e0 + t; e < e1; e += 256)
        atomicAdd(&hist[ebuf[e].x - row0], 1);
    __syncthreads();

    int a0 = hist[2 * t], a1 = hist[2 * t + 1];
    int pv = a0 + a1;
    ps[t] = pv;
    __syncthreads();
    for (int s = 1; s < 256; s <<= 1) {
        int a = (t >= s) ? ps[t - s] : 0;
        __syncthreads();
        ps[t] += a;
        __syncthreads();
    }
    int pe = ps[t] - pv;
    rst[2 * t] = pe;
    rst[2 * t + 1] = pe + a0;
    __syncthreads();

    if (2 * t < nrows)     rowstart[row0 + 2 * t]     = e0 + rst[2 * t];
    if (2 * t + 1 < nrows) rowstart[row0 + 2 * t + 1] = e0 + rst[2 * t + 1];
    if (b == NB - 1 && t == 0) rowstart[NTOT] = Etot;
    hist[2 * t] = rst[2 * t];
    hist[2 * t + 1] = rst[2 * t + 1];
    __syncthreads();

    for (int e = e0 + t; e < e1; e += 256) {
        int2 p = ebuf[e];
        int off = atomicAdd(&hist[p.x - row0], 1);
        csr[e0 + off] = p.y;
    }
}

// ---------------------------------------------------------------------------
// Gather-mean, f32 source (fallback path; proven R5)
// ---------------------------------------------------------------------------
__global__ __launch_bounds__(256)
void gather_mean_f32_kernel(const float* __restrict__ h,
                            const int* __restrict__ csr,
                            const int* __restrict__ rs,
                            unsigned short* __restrict__ msgb, int n)
{
    long gid = (long)blockIdx.x * 256 + threadIdx.x;
    int g = (int)(gid >> 5);
    int lane = (int)(gid & 31);
    if (g >= n) return;

    int s0 = rs[g], s1 = rs[g + 1];
    float4 acc = make_float4(0.f, 0.f, 0.f, 0.f);
    int e = s0;
    for (; e + 4 <= s1; e += 4) {
        int i0 = csr[e], i1 = csr[e + 1], i2 = csr[e + 2], i3 = csr[e + 3];
        float4 v0 = reinterpret_cast<const float4*>(h + (long)i0 * K_DIM)[lane];
        float4 v1 = reinterpret_cast<const float4*>(h + (long)i1 * K_DIM)[lane];
        float4 v2 = reinterpret_cast<const float4*>(h + (long)i2 * K_DIM)[lane];
        float4 v3 = reinterpret_cast<const float4*>(h + (long)i3 * K_DIM)[lane];
        acc.x += (v0.x + v1.x) + (v2.x + v3.x);
        acc.y += (v0.y + v1.y) + (v2.y + v3.y);
        acc.z += (v0.z + v1.z) + (v2.z + v3.z);
        acc.w += (v0.w + v1.w) + (v2.w + v3.w);
    }
    for (; e < s1; ++e) {
        int i0 = csr[e];
        float4 v0 = reinterpret_cast<const float4*>(h + (long)i0 * K_DIM)[lane];
        acc.x += v0.x; acc.y += v0.y; acc.z += v0.z; acc.w += v0.w;
    }
    float rd = 1.0f / fmaxf((float)(s1 - s0), 1.0f);
    ushort4 o;
    o.x = f2bf(acc.x * rd); o.y = f2bf(acc.y * rd);
    o.z = f2bf(acc.z * rd); o.w = f2bf(acc.w * rd);
    reinterpret_cast<ushort4*>(msgb + (long)g * K_DIM)[lane] = o;
}

// ---------------------------------------------------------------------------
// Gather-mean, bf16 source: 16 lanes/row, 16 B (dwordx4) loads, 8-deep MLP.
// 4 rows per wave; 2x in-flight bytes/lane vs R6's 8 B variant.
// ---------------------------------------------------------------------------
__global__ __launch_bounds__(256)
void gather_mean_bf_kernel(const unsigned short* __restrict__ hb,
                           const int* __restrict__ csr,
                           const int* __restrict__ rs,
                           unsigned short* __restrict__ msgb, int n)
{
    long gid = (long)blockIdx.x * 256 + threadIdx.x;
    int g = (int)(gid >> 4);
    int lane = (int)(gid & 15);
    if (g >= n) return;

    int s0 = rs[g], s1 = rs[g + 1];
    float a[8] = {0.f, 0.f, 0.f, 0.f, 0.f, 0.f, 0.f, 0.f};
    const unsigned short* hb_l = hb + lane * 8;

    int e = s0;
    for (; e + 8 <= s1; e += 8) {
        int idx[8];
        #pragma unroll
        for (int i = 0; i < 8; ++i) idx[i] = csr[e + i];
        #pragma unroll
        for (int i = 0; i < 8; ++i) {
            u16x8 v = *reinterpret_cast<const u16x8*>(hb_l + (long)idx[i] * K_DIM);
            #pragma unroll
            for (int j = 0; j < 8; ++j) a[j] += bf2f(v[j]);
        }
    }
    for (; e < s1; ++e) {
        u16x8 v = *reinterpret_cast<const u16x8*>(hb_l + (long)csr[e] * K_DIM);
        #pragma unroll
        for (int j = 0; j < 8; ++j) a[j] += bf2f(v[j]);
    }
    float rd = 1.0f / fmaxf((float)(s1 - s0), 1.0f);
    u16x8 o;
    #pragma unroll
    for (int j = 0; j < 8; ++j) o[j] = f2bf(a[j] * rd);
    *reinterpret_cast<u16x8*>(msgb + (long)g * K_DIM + lane * 8) = o;
}

// ---------------------------------------------------------------------------
// MFMA SAGE GEMM (proven R6, unchanged):
// out = act( h@Ws^T (split h hi/lo) + m@Wn^T (split Wn hi/lo) + b )
// ---------------------------------------------------------------------------
template<int NCOL, bool RELU, bool WRITE_BF>
__global__ __launch_bounds__(256, 3)
void sage_gemm_mfma(const float* __restrict__ h,
                    const unsigned short* __restrict__ msgb,
                    const unsigned short* __restrict__ wsb,
                    const unsigned short* __restrict__ wnh,
                    const unsigned short* __restrict__ wnl,
                    const float* __restrict__ bias,
                    float* __restrict__ out,
                    unsigned short* __restrict__ outb,
                    int n)
{
    constexpr int NCB = NCOL / 16;
    __shared__ bf16x8 Ah[8][64];
    __shared__ bf16x8 Al[8][64];
    __shared__ bf16x8 Ms[8][64];
    __shared__ bf16x8 Bs[NCB][64];
    __shared__ bf16x8 Bh[NCB][64];
    __shared__ bf16x8 Bl[NCB][64];

    const int t    = threadIdx.x;
    const int lane = t & 63;
    const int w    = t >> 6;
    const int row0 = blockIdx.x * 128;

    f32x4 acc[2][NCB];
    #pragma unroll
    for (int rf = 0; rf < 2; ++rf)
        #pragma unroll
        for (int cb = 0; cb < NCB; ++cb)
            acc[rf][cb] = (f32x4){0.f, 0.f, 0.f, 0.f};

    const int arow   = t & 127;
    const int ah2    = t >> 7;
    const int grow_a = min(row0 + arow, n - 1);
    const int arb    = arow >> 4;

    for (int kc = 0; kc < 128; kc += 32) {
        __syncthreads();
        #pragma unroll
        for (int i = 0; i < 2; ++i) {
            int hh = ah2 * 2 + i;
            const float* src = h + (long)grow_a * 128 + kc + hh * 8;
            float4 x = *reinterpret_cast<const float4*>(src);
            float4 y = *reinterpret_cast<const float4*>(src + 4);
            float xs[8] = {x.x, x.y, x.z, x.w, y.x, y.y, y.z, y.w};
            bf16x8 hi8, lo8;
            #pragma unroll
            for (int j = 0; j < 8; ++j) {
                unsigned short hu = f2bf(xs[j]);
                hi8[j] = (short)hu;
                lo8[j] = (short)f2bf(xs[j] - bf2f(hu));
            }
            int li = hh * 16 + (arow & 15);
            Ah[arb][li] = hi8;
            Al[arb][li] = lo8;
            Ms[arb][li] = *reinterpret_cast<const bf16x8*>(
                              msgb + (long)grow_a * 128 + kc + hh * 8);
        }
        if (NCOL == 128) {
            int col = t & 127, h2 = t >> 7;
            #pragma unroll
            for (int i = 0; i < 2; ++i) {
                int hh = h2 * 2 + i;
                int li = hh * 16 + (col & 15);
                int cb = col >> 4;
                long o = (long)col * 128 + kc + hh * 8;
                Bs[cb][li] = *reinterpret_cast<const bf16x8*>(wsb + o);
                Bh[cb][li] = *reinterpret_cast<const bf16x8*>(wnh + o);
                Bl[cb][li] = *reinterpret_cast<const bf16x8*>(wnl + o);
            }
        } else {
            int col = t & 63, hh = t >> 6;
            int li = hh * 16 + (col & 15);
            int cb = col >> 4;
            long o = (long)col * 128 + kc + hh * 8;
            Bs[cb][li] = *reinterpret_cast<const bf16x8*>(wsb + o);
            Bh[cb][li] = *reinterpret_cast<const bf16x8*>(wnh + o);
            Bl[cb][li] = *reinterpret_cast<const bf16x8*>(wnl + o);
        }
        __syncthreads();

        bf16x8 a0h = Ah[2 * w][lane],     a0l = Al[2 * w][lane],     m0 = Ms[2 * w][lane];
        bf16x8 a1h = Ah[2 * w + 1][lane], a1l = Al[2 * w + 1][lane], m1 = Ms[2 * w + 1][lane];
        #pragma unroll
        for (int cb = 0; cb < NCB; ++cb) {
            bf16x8 bs = Bs[cb][lane];
            bf16x8 bh = Bh[cb][lane];
            bf16x8 bl = Bl[cb][lane];
            acc[0][cb] = __builtin_amdgcn_mfma_f32_16x16x32_bf16(a0h, bs, acc[0][cb], 0, 0, 0);
            acc[0][cb] = __builtin_amdgcn_mfma_f32_16x16x32_bf16(a0l, bs, acc[0][cb], 0, 0, 0);
            acc[0][cb] = __builtin_amdgcn_mfma_f32_16x16x32_bf16(m0,  bh, acc[0][cb], 0, 0, 0);
            acc[0][cb] = __builtin_amdgcn_mfma_f32_16x16x32_bf16(m0,  bl, acc[0][cb], 0, 0, 0);
            acc[1][cb] = __builtin_amdgcn_mfma_f32_16x16x32_bf16(a1h, bs, acc[1][cb], 0, 0, 0);
            acc[1][cb] = __builtin_amdgcn_mfma_f32_16x16x32_bf16(a1l, bs, acc[1][cb], 0, 0, 0);
            acc[1][cb] = __builtin_amdgcn_mfma_f32_16x16x32_bf16(m1,  bh, acc[1][cb], 0, 0, 0);
            acc[1][cb] = __builtin_amdgcn_mfma_f32_16x16x32_bf16(m1,  bl, acc[1][cb], 0, 0, 0);
        }
    }

    #pragma unroll
    for (int rf = 0; rf < 2; ++rf) {
        #pragma unroll
        for (int cb = 0; cb < NCB; ++cb) {
            int col = cb * 16 + (lane & 15);
            float bv = bias[col];
            #pragma unroll
            for (int r = 0; r < 4; ++r) {
                int grow = row0 + w * 32 + rf * 16 + (lane >> 4) * 4 + r;
                if (grow < n) {
                    float v = acc[rf][cb][r] + bv;
                    if (RELU) v = fmaxf(v, 0.f);
                    out[(long)grow * NCOL + col] = v;
                    if (WRITE_BF) outb[(long)grow * NCOL + col] = f2bf(v);
                }
            }
        }
    }
}

// ---------------------------------------------------------------------------
// Host (layouts identical to R6; selected by ws_size)
// ---------------------------------------------------------------------------
extern "C" void kernel_launch(void* const* d_in, const int* in_sizes, int n_in,
                              void* d_out, int out_size, void* d_ws, size_t ws_size,
                              hipStream_t stream)
{
    const float* feats   = (const float*)d_in[0];
    const int*   src0    = (const int*)d_in[1];
    const int*   dst0    = (const int*)d_in[2];
    const int*   src1    = (const int*)d_in[3];
    const int*   dst1    = (const int*)d_in[4];
    const int*   src2    = (const int*)d_in[5];
    const int*   dst2    = (const int*)d_in[6];
    const float* Wself0  = (const float*)d_in[10];
    const float* Wneigh0 = (const float*)d_in[11];
    const float* b0      = (const float*)d_in[12];
    const float* Wself1  = (const float*)d_in[13];
    const float* Wneigh1 = (const float*)d_in[14];
    const float* b1      = (const float*)d_in[15];
    const float* Wself2  = (const float*)d_in[16];
    const float* Wneigh2 = (const float*)d_in[17];
    const float* b2      = (const float*)d_in[18];

    const int E0 = in_sizes[1];
    const int E1 = in_sizes[3];
    const int E2 = in_sizes[5];
    const int Etot = E0 + E1 + E2;
    const int N1 = 100000, N2 = 20000, N3 = 5000;

    char* base = (char*)d_ws;
    const bool bfp = ws_size >= 164500000ull;

    unsigned short* feats_bf; float* h1; unsigned short* h1b;
    float* h2; unsigned short* h2b;
    unsigned short* msgb; int2* ebuf; int* csr; int* rowstart;
    int* bcnt; int* bbase; int* bcur; unsigned short* wbf;

    if (bfp) {
        feats_bf = (unsigned short*)base;                  // 128,000,000 B
        h1   = (float*)base;                               // alias post-gather-L0
        h1b  = (unsigned short*)(base + 51200000);
        h2   = (float*)(base + 76800000);
        h2b  = (unsigned short*)(base + 87040000);
        msgb = (unsigned short*)(base + 128000000);        // 25,600,000 B
        csr      = (int*)(base + 153600000);
        rowstart = (int*)(base + 163600000);
        bcnt     = (int*)(base + 164100224);
        bbase    = bcnt + 256;
        bcur     = bbase + 256;
        wbf      = (unsigned short*)(base + 164103296);
    } else {
        feats_bf = nullptr;
        h1   = (float*)base;
        h1b  = nullptr;
        h2   = (float*)(base + 51200000);
        h2b  = nullptr;
        msgb = (unsigned short*)(base + 61440000);
        csr      = (int*)(base + 87040000);
        rowstart = (int*)(base + 97040000);
        bcnt     = (int*)(base + 97540224);
        bbase    = bcnt + 256;
        bcur     = bbase + 256;
        wbf      = (unsigned short*)(base + 97543296);
    }
    ebuf = (int2*)msgb;   // build-phase alias

    // ---- fused prep (conv_feat || conv_w || bucket_count) + rest of build
    const int CFB = bfp ? 2048 : 0;
    hipMemsetAsync(bcnt, 0, 1024, stream);
    prep_kernel<<<CFB + 320 + 512, 256, 0, stream>>>(
        feats, feats_bf, bfp ? 8000000 : 0, CFB,
        Wself0, Wneigh0, Wself1, Wneigh1, Wself2, Wneigh2, wbf,
        dst0, dst1, dst2, E0, E1, Etot, bcnt);
    bucket_scan_kernel<<<1, 256, 0, stream>>>(bcnt, bbase, bcur, Etot);
    bucket_scatter_kernel<<<(Etot + CHUNK - 1) / CHUNK, 256, 0, stream>>>(
        src0, dst0, src1, dst1, src2, dst2, E0, E1, Etot, bcur, ebuf);
    bucket_fill_kernel<<<NB, 256, 0, stream>>>(ebuf, bbase, rowstart, csr, Etot);

    if (bfp) {
        // layer 0
        gather_mean_bf_kernel<<<(N1 * 16 + 255) / 256, 256, 0, stream>>>(
            feats_bf, csr, rowstart, msgb, N1);
        sage_gemm_mfma<128, true, true><<<(N1 + 127) / 128, 256, 0, stream>>>(
            feats, msgb, wbf, wbf + 16384, wbf + 32768, b0, h1, h1b, N1);
        // layer 1
        gather_mean_bf_kernel<<<(N2 * 16 + 255) / 256, 256, 0, stream>>>(
            h1b, csr, rowstart + 100000, msgb, N2);
        sage_gemm_mfma<128, true, true><<<(N2 + 127) / 128, 256, 0, stream>>>(
            h1, msgb, wbf + 49152, wbf + 65536, wbf + 81920, b1, h2, h2b, N2);
        // layer 2
        gather_mean_bf_kernel<<<(N3 * 16 + 255) / 256, 256, 0, stream>>>(
            h2b, csr, rowstart + 120000, msgb, N3);
        sage_gemm_mfma<64, false, false><<<(N3 + 127) / 128, 256, 0, stream>>>(
            h2, msgb, wbf + 98304, wbf + 106496, wbf + 114688, b2,
            (float*)d_out, nullptr, N3);
    } else {
        gather_mean_f32_kernel<<<(N1 * 32 + 255) / 256, 256, 0, stream>>>(
            feats, csr, rowstart, msgb, N1);
        sage_gemm_mfma<128, true, false><<<(N1 + 127) / 128, 256, 0, stream>>>(
            feats, msgb, wbf, wbf + 16384, wbf + 32768, b0, h1, nullptr, N1);
        gather_mean_f32_kernel<<<(N2 * 32 + 255) / 256, 256, 0, stream>>>(
            h1, csr, rowstart + 100000, msgb, N2);
        sage_gemm_mfma<128, true, false><<<(N2 + 127) / 128, 256, 0, stream>>>(
            h1, msgb, wbf + 49152, wbf + 65536, wbf + 81920, b1, h2, nullptr, N2);
        gather_mean_f32_kernel<<<(N3 * 32 + 255) / 256, 256, 0, stream>>>(
            h2, csr, rowstart + 120000, msgb, N3);
        sage_gemm_mfma<64, false, false><<<(N3 + 127) / 128, 256, 0, stream>>>(
            h2, msgb, wbf + 98304, wbf + 106496, wbf + 114688, b2,
            (float*)d_out, nullptr, N3);
    }
}

// Round 8
// 342.724 us; speedup vs baseline: 1.9698x; 1.0411x over previous
//
#include <hip/hip_runtime.h>

#define K_DIM 128
#define NTOT   125000          // 100000 + 20000 + 5000 dst rows
#define RPB    512             // rows per bucket
#define NB     245             // ceil(NTOT / RPB)
#define SRC_BITS 19            // src < 500000 < 2^19
#define SRC_MASK 0x7FFFF

typedef __attribute__((ext_vector_type(8))) short bf16x8;           // 8 bf16 = 4 VGPR
typedef __attribute__((ext_vector_type(8))) unsigned short u16x8;   // 16 B
typedef __attribute__((ext_vector_type(4))) float f32x4;            // MFMA acc

static __device__ __forceinline__ unsigned short f2bf(float f) {
    union { float f; unsigned u; } v; v.f = f;
    unsigned r = v.u + 0x7FFF + ((v.u >> 16) & 1);   // RNE
    return (unsigned short)(r >> 16);
}
static __device__ __forceinline__ float bf2f(unsigned short b) {
    union { unsigned u; float f; } v; v.u = ((unsigned)b) << 16;
    return v.f;
}

// conv_feat worker: grid-strided over uint4 chunks [c0,c1), NCB blocks starting at b0
static __device__ __forceinline__ void conv_feat_part(
    const float* __restrict__ feats, unsigned short* __restrict__ feats_bf,
    int c0, int c1, int b0, int ncb, int b, int t)
{
    int stride = ncb * 256;
    for (long i = c0 + (long)(b - b0) * 256 + t; i < c1; i += stride) {
        float4 a = reinterpret_cast<const float4*>(feats)[2 * i];
        float4 c = reinterpret_cast<const float4*>(feats)[2 * i + 1];
        uint4 o;
        o.x = (unsigned)f2bf(a.x) | ((unsigned)f2bf(a.y) << 16);
        o.y = (unsigned)f2bf(a.z) | ((unsigned)f2bf(a.w) << 16);
        o.z = (unsigned)f2bf(c.x) | ((unsigned)f2bf(c.y) << 16);
        o.w = (unsigned)f2bf(c.z) | ((unsigned)f2bf(c.w) << 16);
        reinterpret_cast<uint4*>(feats_bf)[i] = o;
    }
}

// ---------------------------------------------------------------------------
// Stage 1: blocks [0,512) bucket-histogram dst; [512,832) split W planes.
// ---------------------------------------------------------------------------
__global__ __launch_bounds__(256)
void prep1_kernel(const int* __restrict__ d0, const int* __restrict__ d1,
                  const int* __restrict__ d2, int E0, int E1, int Etot,
                  int* __restrict__ bucket_cnt,
                  const float* __restrict__ w0s, const float* __restrict__ w0n,
                  const float* __restrict__ w1s, const float* __restrict__ w1n,
                  const float* __restrict__ w2s, const float* __restrict__ w2n,
                  unsigned short* __restrict__ wbf)
{
    __shared__ int hist[256];
    int b = blockIdx.x;
    int t = threadIdx.x;

    if (b < 512) {                       // ---- bucket_count
        hist[t] = 0;
        __syncthreads();
        int stride = 512 * 256;
        for (int e = b * 256 + t; e < Etot; e += stride) {
            int row;
            if (e < E0)           row = d0[e];
            else if (e < E0 + E1) row = 100000 + d1[e - E0];
            else                  row = 120000 + d2[e - E0 - E1];
            atomicAdd(&hist[row >> 9], 1);
        }
        __syncthreads();
        if (t < NB && hist[t]) atomicAdd(&bucket_cnt[t], hist[t]);
    } else {                             // ---- conv_w (split planes)
        int idx = (b - 512) * 256 + t;
        if (idx >= 81920) return;
        if (idx < 16384) {
            wbf[idx] = f2bf(w0s[idx]);
        } else if (idx < 32768) {
            int i = idx - 16384; float v = w0n[i];
            unsigned short hi = f2bf(v);
            wbf[16384 + i] = hi;
            wbf[32768 + i] = f2bf(v - bf2f(hi));
        } else if (idx < 49152) {
            int i = idx - 32768;
            wbf[49152 + i] = f2bf(w1s[i]);
        } else if (idx < 65536) {
            int i = idx - 49152; float v = w1n[i];
            unsigned short hi = f2bf(v);
            wbf[65536 + i] = hi;
            wbf[81920 + i] = f2bf(v - bf2f(hi));
        } else if (idx < 73728) {
            int i = idx - 65536;
            wbf[98304 + i] = f2bf(w2s[i]);
        } else {
            int i = idx - 73728; float v = w2n[i];
            unsigned short hi = f2bf(v);
            wbf[106496 + i] = hi;
            wbf[114688 + i] = f2bf(v - bf2f(hi));
        }
    }
}

__global__ __launch_bounds__(256)
void bucket_scan_kernel(const int* __restrict__ bucket_cnt,
                        int* __restrict__ bucket_base,
                        int* __restrict__ bucket_cursor, int Etot)
{
    __shared__ int sm[256];
    int t = threadIdx.x;
    int v = (t < NB) ? bucket_cnt[t] : 0;
    sm[t] = v;
    __syncthreads();
    for (int s = 1; s < 256; s <<= 1) {
        int a = (t >= s) ? sm[t - s] : 0;
        __syncthreads();
        sm[t] += a;
        __syncthreads();
    }
    int excl = sm[t] - v;
    if (t < NB) { bucket_base[t] = excl; bucket_cursor[t] = excl; }
    if (t == 0) bucket_base[NB] = Etot;
}

// ---------------------------------------------------------------------------
// Stage 2: blocks [0,SCB) scatter packed (lrow<<19|src) into bucket-ordered
// ebuf; blocks [SCB, SCB+ncb) run conv_feat over chunks [0, cmid).
// ---------------------------------------------------------------------------
#define CHUNK 4096
__global__ __launch_bounds__(256)
void scatter_conv_kernel(const int* __restrict__ s0, const int* __restrict__ d0,
                         const int* __restrict__ s1, const int* __restrict__ d1,
                         const int* __restrict__ s2, const int* __restrict__ d2,
                         int E0, int E1, int Etot,
                         int* __restrict__ bucket_cursor,
                         int* __restrict__ ebuf,
                         const float* __restrict__ feats,
                         unsigned short* __restrict__ feats_bf,
                         int cmid, int SCB, int ncb)
{
    __shared__ int hist[256];
    __shared__ int start[256];
    int t = threadIdx.x;
    int b = blockIdx.x;

    if (b >= SCB) {                      // ---- conv_feat part A
        conv_feat_part(feats, feats_bf, 0, cmid, SCB, ncb, b, t);
        return;
    }

    int base = b * CHUNK;
    hist[t] = 0;
    __syncthreads();

    #pragma unroll
    for (int i = 0; i < CHUNK / 256; ++i) {
        int e = base + i * 256 + t;
        if (e < Etot) {
            int row;
            if (e < E0)           row = d0[e];
            else if (e < E0 + E1) row = 100000 + d1[e - E0];
            else                  row = 120000 + d2[e - E0 - E1];
            atomicAdd(&hist[row >> 9], 1);
        }
    }
    __syncthreads();
    if (t < NB) {
        int c = hist[t];
        start[t] = c ? atomicAdd(&bucket_cursor[t], c) : 0;
    }
    __syncthreads();
    hist[t] = 0;
    __syncthreads();

    #pragma unroll
    for (int i = 0; i < CHUNK / 256; ++i) {
        int e = base + i * 256 + t;
        if (e < Etot) {
            int row, src;
            if (e < E0)           { row = d0[e];                    src = s0[e]; }
            else if (e < E0 + E1) { row = 100000 + d1[e - E0];      src = s1[e - E0]; }
            else                  { row = 120000 + d2[e - E0 - E1]; src = s2[e - E0 - E1]; }
            int bb = row >> 9;
            int pos = start[bb] + atomicAdd(&hist[bb], 1);
            ebuf[pos] = ((row & (RPB - 1)) << SRC_BITS) | src;
        }
    }
}

// ---------------------------------------------------------------------------
// Stage 3: blocks [0,NB) per-bucket counting sort -> rowstart + csr;
// blocks [NB, NB+ncb) run conv_feat over chunks [cmid, ctot).
// ---------------------------------------------------------------------------
__global__ __launch_bounds__(256)
void fill_conv_kernel(const int* __restrict__ ebuf,
                      const int* __restrict__ bucket_base,
                      int* __restrict__ rowstart,
                      int* __restrict__ csr, int Etot,
                      const float* __restrict__ feats,
                      unsigned short* __restrict__ feats_bf,
                      int cmid, int ctot, int ncb)
{
    __shared__ int hist[RPB];
    __shared__ int ps[256];
    __shared__ int rst[RPB];

    int t = threadIdx.x;
    int b = blockIdx.x;

    if (b >= NB) {                       // ---- conv_feat part B
        conv_feat_part(feats, feats_bf, cmid, ctot, NB, ncb, b, t);
        return;
    }

    int e0 = bucket_base[b], e1 = bucket_base[b + 1];
    int row0 = b << 9;
    int nrows = min(RPB, NTOT - row0);

    hist[t] = 0; hist[t + 256] = 0;
    __syncthreads();
    for (int e = e0 + t; e < e1; e += 256)
        atomicAdd(&hist[(unsigned)ebuf[e] >> SRC_BITS], 1);
    __syncthreads();

    int a0 = hist[2 * t], a1 = hist[2 * t + 1];
    int pv = a0 + a1;
    ps[t] = pv;
    __syncthreads();
    for (int s = 1; s < 256; s <<= 1) {
        int a = (t >= s) ? ps[t - s] : 0;
        __syncthreads();
        ps[t] += a;
        __syncthreads();
    }
    int pe = ps[t] - pv;
    rst[2 * t] = pe;
    rst[2 * t + 1] = pe + a0;
    __syncthreads();

    if (2 * t < nrows)     rowstart[row0 + 2 * t]     = e0 + rst[2 * t];
    if (2 * t + 1 < nrows) rowstart[row0 + 2 * t + 1] = e0 + rst[2 * t + 1];
    if (b == NB - 1 && t == 0) rowstart[NTOT] = Etot;
    hist[2 * t] = rst[2 * t];
    hist[2 * t + 1] = rst[2 * t + 1];
    __syncthreads();

    for (int e = e0 + t; e < e1; e += 256) {
        unsigned p = (unsigned)ebuf[e];
        int off = atomicAdd(&hist[p >> SRC_BITS], 1);
        csr[e0 + off] = p & SRC_MASK;
    }
}

// ---------------------------------------------------------------------------
// Gather-mean, f32 source (fallback path)
// ---------------------------------------------------------------------------
__global__ __launch_bounds__(256)
void gather_mean_f32_kernel(const float* __restrict__ h,
                            const int* __restrict__ csr,
                            const int* __restrict__ rs,
                            unsigned short* __restrict__ msgb, int n)
{
    long gid = (long)blockIdx.x * 256 + threadIdx.x;
    int g = (int)(gid >> 5);
    int lane = (int)(gid & 31);
    if (g >= n) return;

    int s0 = rs[g], s1 = rs[g + 1];
    float4 acc = make_float4(0.f, 0.f, 0.f, 0.f);
    int e = s0;
    for (; e + 4 <= s1; e += 4) {
        int i0 = csr[e], i1 = csr[e + 1], i2 = csr[e + 2], i3 = csr[e + 3];
        float4 v0 = reinterpret_cast<const float4*>(h + (long)i0 * K_DIM)[lane];
        float4 v1 = reinterpret_cast<const float4*>(h + (long)i1 * K_DIM)[lane];
        float4 v2 = reinterpret_cast<const float4*>(h + (long)i2 * K_DIM)[lane];
        float4 v3 = reinterpret_cast<const float4*>(h + (long)i3 * K_DIM)[lane];
        acc.x += (v0.x + v1.x) + (v2.x + v3.x);
        acc.y += (v0.y + v1.y) + (v2.y + v3.y);
        acc.z += (v0.z + v1.z) + (v2.z + v3.z);
        acc.w += (v0.w + v1.w) + (v2.w + v3.w);
    }
    for (; e < s1; ++e) {
        int i0 = csr[e];
        float4 v0 = reinterpret_cast<const float4*>(h + (long)i0 * K_DIM)[lane];
        acc.x += v0.x; acc.y += v0.y; acc.z += v0.z; acc.w += v0.w;
    }
    float rd = 1.0f / fmaxf((float)(s1 - s0), 1.0f);
    ushort4 o;
    o.x = f2bf(acc.x * rd); o.y = f2bf(acc.y * rd);
    o.z = f2bf(acc.z * rd); o.w = f2bf(acc.w * rd);
    reinterpret_cast<ushort4*>(msgb + (long)g * K_DIM)[lane] = o;
}

// ---------------------------------------------------------------------------
// Gather-mean, bf16 source: 16 lanes/row, 16 B loads, 8-deep MLP
// ---------------------------------------------------------------------------
__global__ __launch_bounds__(256)
void gather_mean_bf_kernel(const unsigned short* __restrict__ hb,
                           const int* __restrict__ csr,
                           const int* __restrict__ rs,
                           unsigned short* __restrict__ msgb, int n)
{
    long gid = (long)blockIdx.x * 256 + threadIdx.x;
    int g = (int)(gid >> 4);
    int lane = (int)(gid & 15);
    if (g >= n) return;

    int s0 = rs[g], s1 = rs[g + 1];
    float a[8] = {0.f, 0.f, 0.f, 0.f, 0.f, 0.f, 0.f, 0.f};
    const unsigned short* hb_l = hb + lane * 8;

    int e = s0;
    for (; e + 8 <= s1; e += 8) {
        int idx[8];
        #pragma unroll
        for (int i = 0; i < 8; ++i) idx[i] = csr[e + i];
        #pragma unroll
        for (int i = 0; i < 8; ++i) {
            u16x8 v = *reinterpret_cast<const u16x8*>(hb_l + (long)idx[i] * K_DIM);
            #pragma unroll
            for (int j = 0; j < 8; ++j) a[j] += bf2f(v[j]);
        }
    }
    for (; e < s1; ++e) {
        u16x8 v = *reinterpret_cast<const u16x8*>(hb_l + (long)csr[e] * K_DIM);
        #pragma unroll
        for (int j = 0; j < 8; ++j) a[j] += bf2f(v[j]);
    }
    float rd = 1.0f / fmaxf((float)(s1 - s0), 1.0f);
    u16x8 o;
    #pragma unroll
    for (int j = 0; j < 8; ++j) o[j] = f2bf(a[j] * rd);
    *reinterpret_cast<u16x8*>(msgb + (long)g * K_DIM + lane * 8) = o;
}

// ---------------------------------------------------------------------------
// MFMA SAGE GEMM (proven R6). f32 out written only for rows < nf32.
// ---------------------------------------------------------------------------
template<int NCOL, bool RELU, bool WRITE_BF>
__global__ __launch_bounds__(256, 3)
void sage_gemm_mfma(const float* __restrict__ h,
                    const unsigned short* __restrict__ msgb,
                    const unsigned short* __restrict__ wsb,
                    const unsigned short* __restrict__ wnh,
                    const unsigned short* __restrict__ wnl,
                    const float* __restrict__ bias,
                    float* __restrict__ out,
                    unsigned short* __restrict__ outb,
                    int n, int nf32)
{
    constexpr int NCB = NCOL / 16;
    __shared__ bf16x8 Ah[8][64];
    __shared__ bf16x8 Al[8][64];
    __shared__ bf16x8 Ms[8][64];
    __shared__ bf16x8 Bs[NCB][64];
    __shared__ bf16x8 Bh[NCB][64];
    __shared__ bf16x8 Bl[NCB][64];

    const int t    = threadIdx.x;
    const int lane = t & 63;
    const int w    = t >> 6;
    const int row0 = blockIdx.x * 128;

    f32x4 acc[2][NCB];
    #pragma unroll
    for (int rf = 0; rf < 2; ++rf)
        #pragma unroll
        for (int cb = 0; cb < NCB; ++cb)
            acc[rf][cb] = (f32x4){0.f, 0.f, 0.f, 0.f};

    const int arow   = t & 127;
    const int ah2    = t >> 7;
    const int grow_a = min(row0 + arow, n - 1);
    const int arb    = arow >> 4;

    for (int kc = 0; kc < 128; kc += 32) {
        __syncthreads();
        #pragma unroll
        for (int i = 0; i < 2; ++i) {
            int hh = ah2 * 2 + i;
            const float* src = h + (long)grow_a * 128 + kc + hh * 8;
            float4 x = *reinterpret_cast<const float4*>(src);
            float4 y = *reinterpret_cast<const float4*>(src + 4);
            float xs[8] = {x.x, x.y, x.z, x.w, y.x, y.y, y.z, y.w};
            bf16x8 hi8, lo8;
            #pragma unroll
            for (int j = 0; j < 8; ++j) {
                unsigned short hu = f2bf(xs[j]);
                hi8[j] = (short)hu;
                lo8[j] = (short)f2bf(xs[j] - bf2f(hu));
            }
            int li = hh * 16 + (arow & 15);
            Ah[arb][li] = hi8;
            Al[arb][li] = lo8;
            Ms[arb][li] = *reinterpret_cast<const bf16x8*>(
                              msgb + (long)grow_a * 128 + kc + hh * 8);
        }
        if (NCOL == 128) {
            int col = t & 127, h2 = t >> 7;
            #pragma unroll
            for (int i = 0; i < 2; ++i) {
                int hh = h2 * 2 + i;
                int li = hh * 16 + (col & 15);
                int cb = col >> 4;
                long o = (long)col * 128 + kc + hh * 8;
                Bs[cb][li] = *reinterpret_cast<const bf16x8*>(wsb + o);
                Bh[cb][li] = *reinterpret_cast<const bf16x8*>(wnh + o);
                Bl[cb][li] = *reinterpret_cast<const bf16x8*>(wnl + o);
            }
        } else {
            int col = t & 63, hh = t >> 6;
            int li = hh * 16 + (col & 15);
            int cb = col >> 4;
            long o = (long)col * 128 + kc + hh * 8;
            Bs[cb][li] = *reinterpret_cast<const bf16x8*>(wsb + o);
            Bh[cb][li] = *reinterpret_cast<const bf16x8*>(wnh + o);
            Bl[cb][li] = *reinterpret_cast<const bf16x8*>(wnl + o);
        }
        __syncthreads();

        bf16x8 a0h = Ah[2 * w][lane],     a0l = Al[2 * w][lane],     m0 = Ms[2 * w][lane];
        bf16x8 a1h = Ah[2 * w + 1][lane], a1l = Al[2 * w + 1][lane], m1 = Ms[2 * w + 1][lane];
        #pragma unroll
        for (int cb = 0; cb < NCB; ++cb) {
            bf16x8 bs = Bs[cb][lane];
            bf16x8 bh = Bh[cb][lane];
            bf16x8 bl = Bl[cb][lane];
            acc[0][cb] = __builtin_amdgcn_mfma_f32_16x16x32_bf16(a0h, bs, acc[0][cb], 0, 0, 0);
            acc[0][cb] = __builtin_amdgcn_mfma_f32_16x16x32_bf16(a0l, bs, acc[0][cb], 0, 0, 0);
            acc[0][cb] = __builtin_amdgcn_mfma_f32_16x16x32_bf16(m0,  bh, acc[0][cb], 0, 0, 0);
            acc[0][cb] = __builtin_amdgcn_mfma_f32_16x16x32_bf16(m0,  bl, acc[0][cb], 0, 0, 0);
            acc[1][cb] = __builtin_amdgcn_mfma_f32_16x16x32_bf16(a1h, bs, acc[1][cb], 0, 0, 0);
            acc[1][cb] = __builtin_amdgcn_mfma_f32_16x16x32_bf16(a1l, bs, acc[1][cb], 0, 0, 0);
            acc[1][cb] = __builtin_amdgcn_mfma_f32_16x16x32_bf16(m1,  bh, acc[1][cb], 0, 0, 0);
            acc[1][cb] = __builtin_amdgcn_mfma_f32_16x16x32_bf16(m1,  bl, acc[1][cb], 0, 0, 0);
        }
    }

    #pragma unroll
    for (int rf = 0; rf < 2; ++rf) {
        #pragma unroll
        for (int cb = 0; cb < NCB; ++cb) {
            int col = cb * 16 + (lane & 15);
            float bv = bias[col];
            #pragma unroll
            for (int r = 0; r < 4; ++r) {
                int grow = row0 + w * 32 + rf * 16 + (lane >> 4) * 4 + r;
                if (grow < n) {
                    float v = acc[rf][cb][r] + bv;
                    if (RELU) v = fmaxf(v, 0.f);
                    if (grow < nf32) out[(long)grow * NCOL + col] = v;
                    if (WRITE_BF) outb[(long)grow * NCOL + col] = f2bf(v);
                }
            }
        }
    }
}

// ---------------------------------------------------------------------------
// Host (ws layouts as R6/R7; selected by ws_size)
// ---------------------------------------------------------------------------
extern "C" void kernel_launch(void* const* d_in, const int* in_sizes, int n_in,
                              void* d_out, int out_size, void* d_ws, size_t ws_size,
                              hipStream_t stream)
{
    const float* feats   = (const float*)d_in[0];
    const int*   src0    = (const int*)d_in[1];
    const int*   dst0    = (const int*)d_in[2];
    const int*   src1    = (const int*)d_in[3];
    const int*   dst1    = (const int*)d_in[4];
    const int*   src2    = (const int*)d_in[5];
    const int*   dst2    = (const int*)d_in[6];
    const float* Wself0  = (const float*)d_in[10];
    const float* Wneigh0 = (const float*)d_in[11];
    const float* b0      = (const float*)d_in[12];
    const float* Wself1  = (const float*)d_in[13];
    const float* Wneigh1 = (const float*)d_in[14];
    const float* b1      = (const float*)d_in[15];
    const float* Wself2  = (const float*)d_in[16];
    const float* Wneigh2 = (const float*)d_in[17];
    const float* b2      = (const float*)d_in[18];

    const int E0 = in_sizes[1];
    const int E1 = in_sizes[3];
    const int E2 = in_sizes[5];
    const int Etot = E0 + E1 + E2;
    const int N1 = 100000, N2 = 20000, N3 = 5000;

    char* base = (char*)d_ws;
    const bool bfp = ws_size >= 164500000ull;

    unsigned short* feats_bf; float* h1; unsigned short* h1b;
    float* h2; unsigned short* h2b;
    unsigned short* msgb; int* ebuf; int* csr; int* rowstart;
    int* bcnt; int* bbase; int* bcur; unsigned short* wbf;

    if (bfp) {
        feats_bf = (unsigned short*)base;                  // 128,000,000 B
        h1   = (float*)base;                               // alias post-gather-L0
        h1b  = (unsigned short*)(base + 51200000);
        h2   = (float*)(base + 76800000);
        h2b  = (unsigned short*)(base + 87040000);
        msgb = (unsigned short*)(base + 128000000);        // 25,600,000 B
        csr      = (int*)(base + 153600000);
        rowstart = (int*)(base + 163600000);
        bcnt     = (int*)(base + 164100224);
        bbase    = bcnt + 256;
        bcur     = bbase + 256;
        wbf      = (unsigned short*)(base + 164103296);
    } else {
        feats_bf = nullptr;
        h1   = (float*)base;
        h1b  = nullptr;
        h2   = (float*)(base + 51200000);
        h2b  = nullptr;
        msgb = (unsigned short*)(base + 61440000);
        csr      = (int*)(base + 87040000);
        rowstart = (int*)(base + 97040000);
        bcnt     = (int*)(base + 97540224);
        bbase    = bcnt + 256;
        bcur     = bbase + 256;
        wbf      = (unsigned short*)(base + 97543296);
    }
    ebuf = (int*)msgb;   // build-phase alias (10 MB <= 25.6 MB)

    // ---- build pipeline with conv_feat overlap
    const int SCB  = (Etot + CHUNK - 1) / CHUNK;     // scatter blocks (611)
    const int NCV  = bfp ? 1024 : 0;                 // conv-rider blocks per stage
    const int CTOT = bfp ? 8000000 : 0;              // uint4 chunks in feats
    const int CMID = CTOT / 2;

    hipMemsetAsync(bcnt, 0, 1024, stream);
    prep1_kernel<<<832, 256, 0, stream>>>(
        dst0, dst1, dst2, E0, E1, Etot, bcnt,
        Wself0, Wneigh0, Wself1, Wneigh1, Wself2, Wneigh2, wbf);
    bucket_scan_kernel<<<1, 256, 0, stream>>>(bcnt, bbase, bcur, Etot);
    scatter_conv_kernel<<<SCB + NCV, 256, 0, stream>>>(
        src0, dst0, src1, dst1, src2, dst2, E0, E1, Etot, bcur, ebuf,
        feats, feats_bf, CMID, SCB, NCV);
    fill_conv_kernel<<<NB + NCV, 256, 0, stream>>>(
        ebuf, bbase, rowstart, csr, Etot, feats, feats_bf, CMID, CTOT, NCV);

    if (bfp) {
        // layer 0
        gather_mean_bf_kernel<<<(N1 * 16 + 255) / 256, 256, 0, stream>>>(
            feats_bf, csr, rowstart, msgb, N1);
        sage_gemm_mfma<128, true, true><<<(N1 + 127) / 128, 256, 0, stream>>>(
            feats, msgb, wbf, wbf + 16384, wbf + 32768, b0, h1, h1b, N1, N2);
        // layer 1
        gather_mean_bf_kernel<<<(N2 * 16 + 255) / 256, 256, 0, stream>>>(
            h1b, csr, rowstart + 100000, msgb, N2);
        sage_gemm_mfma<128, true, true><<<(N2 + 127) / 128, 256, 0, stream>>>(
            h1, msgb, wbf + 49152, wbf + 65536, wbf + 81920, b1, h2, h2b, N2, N3);
        // layer 2
        gather_mean_bf_kernel<<<(N3 * 16 + 255) / 256, 256, 0, stream>>>(
            h2b, csr, rowstart + 120000, msgb, N3);
        sage_gemm_mfma<64, false, false><<<(N3 + 127) / 128, 256, 0, stream>>>(
            h2, msgb, wbf + 98304, wbf + 106496, wbf + 114688, b2,
            (float*)d_out, nullptr, N3, N3);
    } else {
        gather_mean_f32_kernel<<<(N1 * 32 + 255) / 256, 256, 0, stream>>>(
            feats, csr, rowstart, msgb, N1);
        sage_gemm_mfma<128, true, false><<<(N1 + 127) / 128, 256, 0, stream>>>(
            feats, msgb, wbf, wbf + 16384, wbf + 32768, b0, h1, nullptr, N1, N1);
        gather_mean_f32_kernel<<<(N2 * 32 + 255) / 256, 256, 0, stream>>>(
            h1, csr, rowstart + 100000, msgb, N2);
        sage_gemm_mfma<128, true, false><<<(N2 + 127) / 128, 256, 0, stream>>>(
            h1, msgb, wbf + 49152, wbf + 65536, wbf + 81920, b1, h2, nullptr, N2, N2);
        gather_mean_f32_kernel<<<(N3 * 32 + 255) / 256, 256, 0, stream>>>(
            h2, csr, rowstart + 120000, msgb, N3);
        sage_gemm_mfma<64, false, false><<<(N3 + 127) / 128, 256, 0, stream>>>(
            h2, msgb, wbf + 98304, wbf + 106496, wbf + 114688, b2,
            (float*)d_out, nullptr, N3, N3);
    }
}